// Round 1
// baseline (3779.752 us; speedup 1.0000x reference)
//
#include <hip/hip_runtime.h>
#include <hip/hip_bf16.h>

#define NB 8
#define N1 4096
#define N2 256
#define DIMD 1024
#define HEADS 16
#define DHD 64
#define KVLEN 4352
#define EPSF 1e-5f
#define L2E 1.44269504088896340736f

typedef __bf16 bf16x8 __attribute__((ext_vector_type(8)));
typedef float f32x4 __attribute__((ext_vector_type(4)));

__device__ __forceinline__ unsigned short f2bf(float f) {
  union { float f; unsigned int u; } v; v.f = f;
  return (unsigned short)((v.u + 0x7FFFu + ((v.u >> 16) & 1u)) >> 16);
}

// ---------------- LayerNorm: f32 row -> bf16 row into combined kv-input ----------------
// rows_per_b rows per batch in input; output row = b*KVLEN + out_off + r
__global__ __launch_bounds__(256) void ln_kernel(
    const float* __restrict__ in, const float* __restrict__ g, const float* __restrict__ bt,
    unsigned short* __restrict__ out, int rows_per_b, int out_off)
{
  int row = blockIdx.x;
  int b = row / rows_per_b;
  int r = row - b * rows_per_b;
  long orow = (long)b * KVLEN + out_off + r;
  const float* rp = in + (long)row * DIMD;
  int t = threadIdx.x;

  float4 x = *reinterpret_cast<const float4*>(rp + t * 4);
  float s = x.x + x.y + x.z + x.w;
  for (int off = 1; off < 64; off <<= 1) s += __shfl_xor(s, off);
  __shared__ float red[8];
  int w = t >> 6;
  if ((t & 63) == 0) red[w] = s;
  __syncthreads();
  float mean = (red[0] + red[1] + red[2] + red[3]) * (1.0f / DIMD);

  float dx = x.x - mean, dy = x.y - mean, dz = x.z - mean, dw = x.w - mean;
  float sq = dx * dx + dy * dy + dz * dz + dw * dw;
  for (int off = 1; off < 64; off <<= 1) sq += __shfl_xor(sq, off);
  if ((t & 63) == 0) red[4 + w] = sq;
  __syncthreads();
  float var = (red[4] + red[5] + red[6] + red[7]) * (1.0f / DIMD);
  float rs = rsqrtf(var + EPSF);

  float4 gg = *reinterpret_cast<const float4*>(g + t * 4);
  float4 bb = *reinterpret_cast<const float4*>(bt + t * 4);
  ushort4 o;
  o.x = f2bf(dx * rs * gg.x + bb.x);
  o.y = f2bf(dy * rs * gg.y + bb.y);
  o.z = f2bf(dz * rs * gg.z + bb.z);
  o.w = f2bf(dw * rs * gg.w + bb.w);
  *reinterpret_cast<ushort4*>(out + orow * DIMD + t * 4) = o;
}

// ---------------- transpose f32[R][C] -> bf16[C][R] ----------------
__global__ __launch_bounds__(256) void transpose_bf16(
    const float* __restrict__ in, unsigned short* __restrict__ out, int R, int C)
{
  __shared__ float t[32][33];
  int r0 = blockIdx.y * 32, c0 = blockIdx.x * 32;
  int tx = threadIdx.x, ty = threadIdx.y;
  for (int p = 0; p < 4; p++)
    t[ty + p * 8][tx] = in[(long)(r0 + ty + p * 8) * C + c0 + tx];
  __syncthreads();
  for (int p = 0; p < 4; p++)
    out[(long)(c0 + ty + p * 8) * R + r0 + tx] = f2bf(t[tx][ty + p * 8]);
}

// ---------------- bf16 MFMA GEMM: A[M][K] @ BT[N][K]^T, 128x128 tile, BK=32 ----------------
// mode 0: A-rows remapped to latent rows of kvin; out -> qbuf [b][h][q][d] bf16
// mode 1: out -> kbuf [b][h][kk][d], vtbuf [b][h][d][kk] bf16
// mode 2: out -> of32 [M][N] f32
#define GPAD 8
__global__ __launch_bounds__(256) void gemm_bf16(
    const unsigned short* __restrict__ A, const unsigned short* __restrict__ BT,
    int M, int N, int K, int mode,
    unsigned short* __restrict__ obf, float* __restrict__ of32,
    unsigned short* __restrict__ kbuf, unsigned short* __restrict__ vtbuf)
{
  __shared__ unsigned short As[128][32 + GPAD];
  __shared__ unsigned short Bs[128][32 + GPAD];
  int m0 = blockIdx.y * 128, n0 = blockIdx.x * 128;
  int tid = threadIdx.x;
  int l = tid & 63, w = tid >> 6;
  int wm = w >> 1, wn = w & 1;
  int lrow = l & 15, lk = (l >> 4) * 8;

  f32x4 acc[4][4] = {};

  for (int k0 = 0; k0 < K; k0 += 32) {
    for (int p = 0; p < 2; p++) {
      int eo = (tid + p * 256) * 8;
      int row = eo >> 5, col = eo & 31;
      long am = m0 + row;
      long ar = (mode == 0) ? ((am >> 8) * KVLEN + N1 + (am & 255)) : am;
      *reinterpret_cast<bf16x8*>(&As[row][col]) =
          *reinterpret_cast<const bf16x8*>(A + ar * K + k0 + col);
      *reinterpret_cast<bf16x8*>(&Bs[row][col]) =
          *reinterpret_cast<const bf16x8*>(BT + (long)(n0 + row) * K + k0 + col);
    }
    __syncthreads();
    bf16x8 af[4], bfr[4];
    for (int i = 0; i < 4; i++)
      af[i] = *reinterpret_cast<bf16x8*>(&As[wm * 64 + i * 16 + lrow][lk]);
    for (int j = 0; j < 4; j++)
      bfr[j] = *reinterpret_cast<bf16x8*>(&Bs[wn * 64 + j * 16 + lrow][lk]);
    for (int i = 0; i < 4; i++)
      for (int j = 0; j < 4; j++)
        acc[i][j] = __builtin_amdgcn_mfma_f32_16x16x32_bf16(af[i], bfr[j], acc[i][j], 0, 0, 0);
    __syncthreads();
  }

  for (int i = 0; i < 4; i++)
    for (int j = 0; j < 4; j++)
      for (int r = 0; r < 4; r++) {
        int m = m0 + wm * 64 + i * 16 + (l >> 4) * 4 + r;
        int n = n0 + wn * 64 + j * 16 + (l & 15);
        float v = acc[i][j][r];
        if (mode == 0) {
          int b = m >> 8, qq = m & 255, h = n >> 6, d = n & 63;
          obf[(((long)(b * HEADS + h) * N2 + qq) << 6) + d] = f2bf(v);
        } else if (mode == 1) {
          int b = m / KVLEN, kk = m - b * KVLEN;
          if (n < DIMD) {
            int h = n >> 6, d = n & 63;
            kbuf[(((long)(b * HEADS + h) * KVLEN + kk) << 6) + d] = f2bf(v);
          } else {
            int c = n - DIMD, h = c >> 6, d = c & 63;
            vtbuf[((long)(b * HEADS + h) * DHD + d) * KVLEN + kk] = f2bf(v);
          }
        } else {
          of32[(long)m * DIMD + n] = v;
        }
      }
}

// ---------------- flash attention: 1 block = (b,h, 64 q rows), 4 waves x 16 q rows ----------------
__global__ __launch_bounds__(256) void attn_kernel(
    const unsigned short* __restrict__ qb, const unsigned short* __restrict__ kb,
    const unsigned short* __restrict__ vtb, unsigned short* __restrict__ attn)
{
  __shared__ unsigned short Ks[64][72];
  __shared__ unsigned short Vs[64][72];
  __shared__ unsigned short Ps[4][16][72];
  int qt = blockIdx.x, bh = blockIdx.y;
  int tid = threadIdx.x, l = tid & 63, w = tid >> 6;
  int lrow = l & 15, lk = (l >> 4) * 8;

  const unsigned short* qp = qb + ((long)bh * N2 + qt * 64 + w * 16) * DHD;
  const unsigned short* kp = kb + (long)bh * KVLEN * DHD;
  const unsigned short* vp = vtb + (long)bh * DHD * KVLEN;

  bf16x8 qa[2];
  qa[0] = *reinterpret_cast<const bf16x8*>(qp + lrow * DHD + lk);
  qa[1] = *reinterpret_cast<const bf16x8*>(qp + lrow * DHD + 32 + lk);

  f32x4 O[4] = {};
  float mrow[4] = {-1e30f, -1e30f, -1e30f, -1e30f};
  float lsum[4] = {0.f, 0.f, 0.f, 0.f};

  for (int blk = 0; blk < KVLEN / 64; blk++) {
    __syncthreads();
    for (int p = 0; p < 2; p++) {
      int eo = (tid + p * 256) * 8;
      int row = eo >> 6, col = eo & 63;
      *reinterpret_cast<bf16x8*>(&Ks[row][col]) =
          *reinterpret_cast<const bf16x8*>(kp + (long)(blk * 64 + row) * DHD + col);
      *reinterpret_cast<bf16x8*>(&Vs[row][col]) =
          *reinterpret_cast<const bf16x8*>(vp + (long)row * KVLEN + blk * 64 + col);
    }
    __syncthreads();

    f32x4 S[4];
    for (int nt = 0; nt < 4; nt++) {
      f32x4 s = {};
      for (int kt = 0; kt < 2; kt++) {
        bf16x8 bk = *reinterpret_cast<bf16x8*>(&Ks[nt * 16 + lrow][kt * 32 + lk]);
        s = __builtin_amdgcn_mfma_f32_16x16x32_bf16(qa[kt], bk, s, 0, 0, 0);
      }
      S[nt] = s * 0.125f;
    }

    float mx[4], rsum[4];
    for (int r = 0; r < 4; r++) {
      float v = fmaxf(fmaxf(S[0][r], S[1][r]), fmaxf(S[2][r], S[3][r]));
      for (int off = 1; off < 16; off <<= 1) v = fmaxf(v, __shfl_xor(v, off));
      mx[r] = v;
    }
    float fac[4];
    for (int r = 0; r < 4; r++) {
      float mn = fmaxf(mrow[r], mx[r]);
      fac[r] = exp2f((mrow[r] - mn) * L2E);
      mrow[r] = mn;
      rsum[r] = 0.f;
    }
    for (int nt = 0; nt < 4; nt++)
      for (int r = 0; r < 4; r++) {
        float p = exp2f((S[nt][r] - mrow[r]) * L2E);
        rsum[r] += p;
        Ps[w][(l >> 4) * 4 + r][nt * 16 + lrow] = f2bf(p);
      }
    for (int r = 0; r < 4; r++) {
      float v = rsum[r];
      for (int off = 1; off < 16; off <<= 1) v += __shfl_xor(v, off);
      lsum[r] = lsum[r] * fac[r] + v;
    }
    for (int dt = 0; dt < 4; dt++)
      for (int r = 0; r < 4; r++) O[dt][r] *= fac[r];

    asm volatile("s_waitcnt lgkmcnt(0)" ::: "memory");
    bf16x8 pa[2];
    pa[0] = *reinterpret_cast<bf16x8*>(&Ps[w][lrow][lk]);
    pa[1] = *reinterpret_cast<bf16x8*>(&Ps[w][lrow][32 + lk]);
    for (int dt = 0; dt < 4; dt++)
      for (int kt = 0; kt < 2; kt++) {
        bf16x8 bv = *reinterpret_cast<bf16x8*>(&Vs[dt * 16 + lrow][kt * 32 + lk]);
        O[dt] = __builtin_amdgcn_mfma_f32_16x16x32_bf16(pa[kt], bv, O[dt], 0, 0, 0);
      }
  }

  int b = bh >> 4, h = bh & 15;
  for (int dt = 0; dt < 4; dt++)
    for (int r = 0; r < 4; r++) {
      int grow = b * N2 + qt * 64 + w * 16 + (l >> 4) * 4 + r;
      int col = h * DHD + dt * 16 + lrow;
      attn[(long)grow * DIMD + col] = f2bf(O[dt][r] / lsum[r]);
    }
}

// ---------------- launch ----------------
extern "C" void kernel_launch(void* const* d_in, const int* in_sizes, int n_in,
                              void* d_out, int out_size, void* d_ws, size_t ws_size,
                              hipStream_t stream) {
  const float* x    = (const float*)d_in[0];
  const float* lat  = (const float*)d_in[1];
  const float* g1   = (const float*)d_in[2];
  const float* b1   = (const float*)d_in[3];
  const float* g2   = (const float*)d_in[4];
  const float* b2   = (const float*)d_in[5];
  const float* Wq   = (const float*)d_in[6];
  const float* Wkv  = (const float*)d_in[7];
  const float* Wout = (const float*)d_in[8];
  float* out = (float*)d_out;

  char* ws = (char*)d_ws;
  size_t off = 0;
  auto alloc = [&](size_t bytes) -> void* {
    void* p = ws + off;
    off += (bytes + 255) & ~(size_t)255;
    return p;
  };
  unsigned short* kvin  = (unsigned short*)alloc((size_t)NB * KVLEN * DIMD * 2);
  unsigned short* WqT   = (unsigned short*)alloc((size_t)DIMD * DIMD * 2);
  unsigned short* WkvT  = (unsigned short*)alloc((size_t)2 * DIMD * DIMD * 2);
  unsigned short* WoutT = (unsigned short*)alloc((size_t)DIMD * DIMD * 2);
  unsigned short* qbuf  = (unsigned short*)alloc((size_t)NB * N2 * DIMD * 2);
  unsigned short* kbuf  = (unsigned short*)alloc((size_t)NB * HEADS * KVLEN * DHD * 2);
  unsigned short* vtbuf = (unsigned short*)alloc((size_t)NB * HEADS * KVLEN * DHD * 2);
  unsigned short* attn  = (unsigned short*)alloc((size_t)NB * N2 * DIMD * 2);
  if (off > ws_size) return;  // workspace too small: fail loudly (output stays zero)

  // weights -> bf16 [N][K]
  transpose_bf16<<<dim3(DIMD / 32, DIMD / 32), dim3(32, 8), 0, stream>>>(Wq, WqT, DIMD, DIMD);
  transpose_bf16<<<dim3(2 * DIMD / 32, DIMD / 32), dim3(32, 8), 0, stream>>>(Wkv, WkvT, DIMD, 2 * DIMD);
  transpose_bf16<<<dim3(DIMD / 32, DIMD / 32), dim3(32, 8), 0, stream>>>(Wout, WoutT, DIMD, DIMD);

  // layernorms into combined kv-input buffer
  ln_kernel<<<NB * N1, 256, 0, stream>>>(x, g1, b1, kvin, N1, 0);
  ln_kernel<<<NB * N2, 256, 0, stream>>>(lat, g2, b2, kvin, N2, N1);

  // Q = ln @ Wq   (M=2048, N=1024)
  gemm_bf16<<<dim3(8, 16), 256, 0, stream>>>(kvin, WqT, NB * N2, DIMD, DIMD, 0,
                                             qbuf, nullptr, nullptr, nullptr);
  // KV = [xn;ln] @ Wkv  (M=34816, N=2048)
  gemm_bf16<<<dim3(16, 272), 256, 0, stream>>>(kvin, WkvT, NB * KVLEN, 2 * DIMD, DIMD, 1,
                                               nullptr, nullptr, kbuf, vtbuf);
  // attention
  attn_kernel<<<dim3(4, NB * HEADS), 256, 0, stream>>>(qbuf, kbuf, vtbuf, attn);
  // out = attn @ Wout  (M=2048, N=1024) -> f32
  gemm_bf16<<<dim3(8, 16), 256, 0, stream>>>(attn, WoutT, NB * N2, DIMD, DIMD, 2,
                                             nullptr, out, nullptr, nullptr);
}

// Round 2
// 3652.779 us; speedup vs baseline: 1.0348x; 1.0348x over previous
//
#include <hip/hip_runtime.h>
#include <hip/hip_bf16.h>

#define NB 8
#define N1 4096
#define N2 256
#define DIMD 1024
#define HEADS 16
#define DHD 64
#define KVLEN 4352
#define EPSF 1e-5f
#define L2E 1.44269504088896340736f

typedef __bf16 bf16x8 __attribute__((ext_vector_type(8)));
typedef float f32x4 __attribute__((ext_vector_type(4)));

__device__ __forceinline__ unsigned short f2bf(float f) {
  union { float f; unsigned int u; } v; v.f = f;
  return (unsigned short)((v.u + 0x7FFFu + ((v.u >> 16) & 1u)) >> 16);
}

// async global->LDS, 16B per lane; LDS dest is wave-uniform base + lane*16
__device__ __forceinline__ void gload_lds16(const void* g, void* l) {
  __builtin_amdgcn_global_load_lds(
      (const __attribute__((address_space(1))) void*)g,
      (__attribute__((address_space(3))) void*)l, 16, 0, 0);
}

// ---------------- LayerNorm: f32 row -> bf16 row into combined kv-input ----------------
__global__ __launch_bounds__(256) void ln_kernel(
    const float* __restrict__ in, const float* __restrict__ g, const float* __restrict__ bt,
    unsigned short* __restrict__ out, int rows_per_b, int out_off)
{
  int row = blockIdx.x;
  int b = row / rows_per_b;
  int r = row - b * rows_per_b;
  long orow = (long)b * KVLEN + out_off + r;
  const float* rp = in + (long)row * DIMD;
  int t = threadIdx.x;

  float4 x = *reinterpret_cast<const float4*>(rp + t * 4);
  float s = x.x + x.y + x.z + x.w;
  for (int off = 1; off < 64; off <<= 1) s += __shfl_xor(s, off);
  __shared__ float red[8];
  int w = t >> 6;
  if ((t & 63) == 0) red[w] = s;
  __syncthreads();
  float mean = (red[0] + red[1] + red[2] + red[3]) * (1.0f / DIMD);

  float dx = x.x - mean, dy = x.y - mean, dz = x.z - mean, dw = x.w - mean;
  float sq = dx * dx + dy * dy + dz * dz + dw * dw;
  for (int off = 1; off < 64; off <<= 1) sq += __shfl_xor(sq, off);
  if ((t & 63) == 0) red[4 + w] = sq;
  __syncthreads();
  float var = (red[4] + red[5] + red[6] + red[7]) * (1.0f / DIMD);
  float rs = rsqrtf(var + EPSF);

  float4 gg = *reinterpret_cast<const float4*>(g + t * 4);
  float4 bb = *reinterpret_cast<const float4*>(bt + t * 4);
  ushort4 o;
  o.x = f2bf(dx * rs * gg.x + bb.x);
  o.y = f2bf(dy * rs * gg.y + bb.y);
  o.z = f2bf(dz * rs * gg.z + bb.z);
  o.w = f2bf(dw * rs * gg.w + bb.w);
  *reinterpret_cast<ushort4*>(out + orow * DIMD + t * 4) = o;
}

// ---------------- transpose f32[R][C] -> bf16[C][R] (weights, tiny) ----------------
__global__ __launch_bounds__(256) void transpose_bf16(
    const float* __restrict__ in, unsigned short* __restrict__ out, int R, int C)
{
  __shared__ float t[32][33];
  int r0 = blockIdx.y * 32, c0 = blockIdx.x * 32;
  int tx = threadIdx.x, ty = threadIdx.y;
  for (int p = 0; p < 4; p++)
    t[ty + p * 8][tx] = in[(long)(r0 + ty + p * 8) * C + c0 + tx];
  __syncthreads();
  for (int p = 0; p < 4; p++)
    out[(long)(c0 + ty + p * 8) * R + r0 + tx] = f2bf(t[tx][ty + p * 8]);
}

// ---------------- bf16 MFMA GEMM (m97 structure): A[M][K] @ BT[N][K]^T ----------------
// 128x128 tile, BK=32, linear LDS, global_load_lds width=16 staging.
// mode 0: A rows remapped to latent rows of kvin; out -> qbuf [b][h][q][d] bf16
// mode 1: out -> kbuf/vbuf [b][h][kk][d] bf16 (V natural layout; transpose done later)
// mode 2: out -> of32 [M][N] f32
__global__ __launch_bounds__(256) void gemm2(
    const unsigned short* __restrict__ A, const unsigned short* __restrict__ BT,
    int M, int N, int K, int mode,
    unsigned short* __restrict__ obf, float* __restrict__ of32,
    unsigned short* __restrict__ kbuf, unsigned short* __restrict__ vbuf)
{
  __shared__ unsigned short As[128 * 32];
  __shared__ unsigned short Bs[128 * 32];
  int tid = threadIdx.x, l = tid & 63, w = tid >> 6;
  int m0 = blockIdx.y * 128, n0 = blockIdx.x * 128;
  int wm = w >> 1, wn = w & 1;
  int lrow = l & 15, lk = (l >> 4) * 8;

  // staging map: chunk c (16 rows = 1KB) -> wave c&3, issue c>>2; lane l: row c*16+(l>>2), col (l&3)*8
  int sr = l >> 2, scol = (l & 3) * 8;
  long am0 = m0 + w * 16 + sr, am1 = m0 + (w + 4) * 16 + sr;
  if (mode == 0) {
    am0 = (am0 >> 8) * KVLEN + N1 + (am0 & 255);
    am1 = (am1 >> 8) * KVLEN + N1 + (am1 & 255);
  }
  const unsigned short* gA0 = A + am0 * K + scol;
  const unsigned short* gA1 = A + am1 * K + scol;
  const unsigned short* gB0 = BT + (long)(n0 + w * 16 + sr) * K + scol;
  const unsigned short* gB1 = BT + (long)(n0 + (w + 4) * 16 + sr) * K + scol;
  unsigned short* lA0 = As + w * 512;
  unsigned short* lA1 = As + (w + 4) * 512;
  unsigned short* lB0 = Bs + w * 512;
  unsigned short* lB1 = Bs + (w + 4) * 512;

  f32x4 acc[4][4] = {};

  for (int k0 = 0; k0 < K; k0 += 32) {
    gload_lds16(gA0, lA0);
    gload_lds16(gA1, lA1);
    gload_lds16(gB0, lB0);
    gload_lds16(gB1, lB1);
    gA0 += 32; gA1 += 32; gB0 += 32; gB1 += 32;
    __syncthreads();  // drains vmcnt -> staged data visible
    bf16x8 af[4], bfr[4];
    for (int i = 0; i < 4; i++)
      af[i] = *reinterpret_cast<bf16x8*>(&As[(wm * 64 + i * 16 + lrow) * 32 + lk]);
    for (int j = 0; j < 4; j++)
      bfr[j] = *reinterpret_cast<bf16x8*>(&Bs[(wn * 64 + j * 16 + lrow) * 32 + lk]);
    for (int i = 0; i < 4; i++)
      for (int j = 0; j < 4; j++)
        acc[i][j] = __builtin_amdgcn_mfma_f32_16x16x32_bf16(af[i], bfr[j], acc[i][j], 0, 0, 0);
    __syncthreads();  // protect LDS before next-iter staging
  }

  for (int i = 0; i < 4; i++)
    for (int j = 0; j < 4; j++)
      for (int r = 0; r < 4; r++) {
        int m = m0 + wm * 64 + i * 16 + (l >> 4) * 4 + r;
        int n = n0 + wn * 64 + j * 16 + (l & 15);
        float v = acc[i][j][r];
        if (mode == 0) {
          int b = m >> 8, qq = m & 255, h = n >> 6, d = n & 63;
          obf[(((long)(b * HEADS + h) * N2 + qq) << 6) + d] = f2bf(v);
        } else if (mode == 1) {
          int b = m / KVLEN, kk = m - b * KVLEN;  // 128 | KVLEN, so tile is single-batch
          unsigned short* dst; int nn;
          if (n < DIMD) { dst = kbuf; nn = n; } else { dst = vbuf; nn = n - DIMD; }
          int h = nn >> 6, d = nn & 63;
          dst[(((long)(b * HEADS + h) * KVLEN + kk) << 6) + d] = f2bf(v);
        } else {
          of32[(long)m * N + n] = v;
        }
      }
}

// ---------------- V transpose: [b][h][kk][d] -> [b][h][d][kk], 64x64 LDS tiles ----------------
__global__ __launch_bounds__(256) void vtrans(
    const unsigned short* __restrict__ in, unsigned short* __restrict__ out)
{
  __shared__ unsigned short t[64][70];  // pad 70: column reads spread banks
  int bh = blockIdx.y, k0 = blockIdx.x * 64;
  int tid = threadIdx.x;
  const unsigned short* ip = in + ((long)bh * KVLEN + k0) * DHD;
  for (int p = 0; p < 2; p++) {
    int eo = (tid + p * 256) * 8;
    int r = eo >> 6, c = eo & 63;  // r=kk, c=d0
    *reinterpret_cast<bf16x8*>(&t[r][c]) =
        *reinterpret_cast<const bf16x8*>(ip + (long)r * DHD + c);
  }
  __syncthreads();
  unsigned short* op = out + (long)bh * DHD * KVLEN + k0;
  for (int p = 0; p < 2; p++) {
    int eo = (tid + p * 256) * 8;
    int dd = eo >> 6, kc = eo & 63;  // output row d, kk-chunk
    ushort4 o0, o1;
    o0.x = t[kc + 0][dd]; o0.y = t[kc + 1][dd];
    o0.z = t[kc + 2][dd]; o0.w = t[kc + 3][dd];
    o1.x = t[kc + 4][dd]; o1.y = t[kc + 5][dd];
    o1.z = t[kc + 6][dd]; o1.w = t[kc + 7][dd];
    *reinterpret_cast<ushort4*>(op + (long)dd * KVLEN + kc) = o0;
    *reinterpret_cast<ushort4*>(op + (long)dd * KVLEN + kc + 4) = o1;
  }
}

// ---------------- flash attention: 1 block = (b,h, 64 q rows), 4 waves x 16 q rows ----------------
__global__ __launch_bounds__(256) void attn_kernel(
    const unsigned short* __restrict__ qb, const unsigned short* __restrict__ kb,
    const unsigned short* __restrict__ vtb, unsigned short* __restrict__ attn)
{
  __shared__ unsigned short Ks[64][72];
  __shared__ unsigned short Vs[64][72];
  __shared__ unsigned short Ps[4][16][72];
  int qt = blockIdx.x, bh = blockIdx.y;
  int tid = threadIdx.x, l = tid & 63, w = tid >> 6;
  int lrow = l & 15, lk = (l >> 4) * 8;

  const unsigned short* qp = qb + ((long)bh * N2 + qt * 64 + w * 16) * DHD;
  const unsigned short* kp = kb + (long)bh * KVLEN * DHD;
  const unsigned short* vp = vtb + (long)bh * DHD * KVLEN;

  bf16x8 qa[2];
  qa[0] = *reinterpret_cast<const bf16x8*>(qp + lrow * DHD + lk);
  qa[1] = *reinterpret_cast<const bf16x8*>(qp + lrow * DHD + 32 + lk);

  f32x4 O[4] = {};
  float mrow[4] = {-1e30f, -1e30f, -1e30f, -1e30f};
  float lsum[4] = {0.f, 0.f, 0.f, 0.f};

  for (int blk = 0; blk < KVLEN / 64; blk++) {
    __syncthreads();
    for (int p = 0; p < 2; p++) {
      int eo = (tid + p * 256) * 8;
      int row = eo >> 6, col = eo & 63;
      *reinterpret_cast<bf16x8*>(&Ks[row][col]) =
          *reinterpret_cast<const bf16x8*>(kp + (long)(blk * 64 + row) * DHD + col);
      *reinterpret_cast<bf16x8*>(&Vs[row][col]) =
          *reinterpret_cast<const bf16x8*>(vp + (long)row * KVLEN + blk * 64 + col);
    }
    __syncthreads();

    f32x4 S[4];
    for (int nt = 0; nt < 4; nt++) {
      f32x4 s = {};
      for (int kt = 0; kt < 2; kt++) {
        bf16x8 bk = *reinterpret_cast<bf16x8*>(&Ks[nt * 16 + lrow][kt * 32 + lk]);
        s = __builtin_amdgcn_mfma_f32_16x16x32_bf16(qa[kt], bk, s, 0, 0, 0);
      }
      S[nt] = s * 0.125f;
    }

    float mx[4], rsum[4];
    for (int r = 0; r < 4; r++) {
      float v = fmaxf(fmaxf(S[0][r], S[1][r]), fmaxf(S[2][r], S[3][r]));
      for (int off = 1; off < 16; off <<= 1) v = fmaxf(v, __shfl_xor(v, off));
      mx[r] = v;
    }
    float fac[4];
    for (int r = 0; r < 4; r++) {
      float mn = fmaxf(mrow[r], mx[r]);
      fac[r] = exp2f((mrow[r] - mn) * L2E);
      mrow[r] = mn;
      rsum[r] = 0.f;
    }
    for (int nt = 0; nt < 4; nt++)
      for (int r = 0; r < 4; r++) {
        float p = exp2f((S[nt][r] - mrow[r]) * L2E);
        rsum[r] += p;
        Ps[w][(l >> 4) * 4 + r][nt * 16 + lrow] = f2bf(p);
      }
    for (int r = 0; r < 4; r++) {
      float v = rsum[r];
      for (int off = 1; off < 16; off <<= 1) v += __shfl_xor(v, off);
      lsum[r] = lsum[r] * fac[r] + v;
    }
    for (int dt = 0; dt < 4; dt++)
      for (int r = 0; r < 4; r++) O[dt][r] *= fac[r];

    asm volatile("s_waitcnt lgkmcnt(0)" ::: "memory");
    bf16x8 pa[2];
    pa[0] = *reinterpret_cast<bf16x8*>(&Ps[w][lrow][lk]);
    pa[1] = *reinterpret_cast<bf16x8*>(&Ps[w][lrow][32 + lk]);
    for (int dt = 0; dt < 4; dt++)
      for (int kt = 0; kt < 2; kt++) {
        bf16x8 bv = *reinterpret_cast<bf16x8*>(&Vs[dt * 16 + lrow][kt * 32 + lk]);
        O[dt] = __builtin_amdgcn_mfma_f32_16x16x32_bf16(pa[kt], bv, O[dt], 0, 0, 0);
      }
  }

  int b = bh >> 4, h = bh & 15;
  for (int dt = 0; dt < 4; dt++)
    for (int r = 0; r < 4; r++) {
      int grow = b * N2 + qt * 64 + w * 16 + (l >> 4) * 4 + r;
      int col = h * DHD + dt * 16 + lrow;
      attn[(long)grow * DIMD + col] = f2bf(O[dt][r] / lsum[r]);
    }
}

// ---------------- launch ----------------
extern "C" void kernel_launch(void* const* d_in, const int* in_sizes, int n_in,
                              void* d_out, int out_size, void* d_ws, size_t ws_size,
                              hipStream_t stream) {
  const float* x    = (const float*)d_in[0];
  const float* lat  = (const float*)d_in[1];
  const float* g1   = (const float*)d_in[2];
  const float* b1   = (const float*)d_in[3];
  const float* g2   = (const float*)d_in[4];
  const float* b2   = (const float*)d_in[5];
  const float* Wq   = (const float*)d_in[6];
  const float* Wkv  = (const float*)d_in[7];
  const float* Wout = (const float*)d_in[8];
  float* out = (float*)d_out;

  char* ws = (char*)d_ws;
  size_t off = 0;
  auto alloc = [&](size_t bytes) -> void* {
    void* p = ws + off;
    off += (bytes + 255) & ~(size_t)255;
    return p;
  };
  unsigned short* kvin  = (unsigned short*)alloc((size_t)NB * KVLEN * DIMD * 2);
  unsigned short* WqT   = (unsigned short*)alloc((size_t)DIMD * DIMD * 2);
  unsigned short* WkvT  = (unsigned short*)alloc((size_t)2 * DIMD * DIMD * 2);
  unsigned short* WoutT = (unsigned short*)alloc((size_t)DIMD * DIMD * 2);
  unsigned short* qbuf  = (unsigned short*)alloc((size_t)NB * N2 * DIMD * 2);
  unsigned short* kbuf  = (unsigned short*)alloc((size_t)NB * HEADS * KVLEN * DHD * 2);
  unsigned short* vbuf  = (unsigned short*)alloc((size_t)NB * HEADS * KVLEN * DHD * 2);
  unsigned short* attn  = (unsigned short*)alloc((size_t)NB * N2 * DIMD * 2);
  if (off > ws_size) return;  // workspace too small: fail loudly (output stays zero)
  // vtbuf aliases kvin: kvin is dead after the KV GEMM, and sizes match exactly
  // (NB*KVLEN*DIMD == NB*HEADS*DHD*KVLEN). vtrans runs after gemm2(mode 1) on the
  // same stream, so ordering is safe.
  unsigned short* vtbuf = kvin;

  // weights -> bf16 [N][K]
  transpose_bf16<<<dim3(DIMD / 32, DIMD / 32), dim3(32, 8), 0, stream>>>(Wq, WqT, DIMD, DIMD);
  transpose_bf16<<<dim3(2 * DIMD / 32, DIMD / 32), dim3(32, 8), 0, stream>>>(Wkv, WkvT, DIMD, 2 * DIMD);
  transpose_bf16<<<dim3(DIMD / 32, DIMD / 32), dim3(32, 8), 0, stream>>>(Wout, WoutT, DIMD, DIMD);

  // layernorms into combined kv-input buffer
  ln_kernel<<<NB * N1, 256, 0, stream>>>(x, g1, b1, kvin, N1, 0);
  ln_kernel<<<NB * N2, 256, 0, stream>>>(lat, g2, b2, kvin, N2, N1);

  // Q = ln @ Wq   (M=2048, N=1024)
  gemm2<<<dim3(8, 16), 256, 0, stream>>>(kvin, WqT, NB * N2, DIMD, DIMD, 0,
                                         qbuf, nullptr, nullptr, nullptr);
  // KV = [xn;ln] @ Wkv  (M=34816, N=2048) -> K,V natural [b][h][kk][d]
  gemm2<<<dim3(16, 272), 256, 0, stream>>>(kvin, WkvT, NB * KVLEN, 2 * DIMD, DIMD, 1,
                                           nullptr, nullptr, kbuf, vbuf);
  // V -> V^T  [b][h][d][kk]
  vtrans<<<dim3(KVLEN / 64, NB * HEADS), 256, 0, stream>>>(vbuf, vtbuf);
  // attention
  attn_kernel<<<dim3(4, NB * HEADS), 256, 0, stream>>>(qbuf, kbuf, vtbuf, attn);
  // out = attn @ Wout  (M=2048, N=1024) -> f32
  gemm2<<<dim3(8, 16), 256, 0, stream>>>(attn, WoutT, NB * N2, DIMD, DIMD, 2,
                                         nullptr, out, nullptr, nullptr);
}

// Round 3
// 709.287 us; speedup vs baseline: 5.3289x; 5.1499x over previous
//
#include <hip/hip_runtime.h>
#include <hip/hip_bf16.h>

#define NB 8
#define N1 4096
#define N2 256
#define DIMD 1024
#define HEADS 16
#define DHD 64
#define KVLEN 4352
#define EPSF 1e-5f
#define L2E 1.44269504088896340736f

typedef __bf16 bf16x8 __attribute__((ext_vector_type(8)));
typedef float f32x4 __attribute__((ext_vector_type(4)));

__device__ __forceinline__ unsigned short f2bf(float f) {
  union { float f; unsigned int u; } v; v.f = f;
  return (unsigned short)((v.u + 0x7FFFu + ((v.u >> 16) & 1u)) >> 16);
}

// async global->LDS, 16B per lane; LDS dest is wave-uniform base + lane*16
__device__ __forceinline__ void gload_lds16(const void* g, void* l) {
  __builtin_amdgcn_global_load_lds(
      (const __attribute__((address_space(1))) void*)g,
      (__attribute__((address_space(3))) void*)l, 16, 0, 0);
}

// ---------------- LayerNorm: f32 row -> bf16 row into combined kv-input ----------------
__global__ __launch_bounds__(256) void ln_kernel(
    const float* __restrict__ in, const float* __restrict__ g, const float* __restrict__ bt,
    unsigned short* __restrict__ out, int rows_per_b, int out_off)
{
  int row = blockIdx.x;
  int b = row / rows_per_b;
  int r = row - b * rows_per_b;
  long orow = (long)b * KVLEN + out_off + r;
  const float* rp = in + (long)row * DIMD;
  int t = threadIdx.x;

  float4 x = *reinterpret_cast<const float4*>(rp + t * 4);
  float s = x.x + x.y + x.z + x.w;
  #pragma unroll
  for (int off = 1; off < 64; off <<= 1) s += __shfl_xor(s, off);
  __shared__ float red[8];
  int w = t >> 6;
  if ((t & 63) == 0) red[w] = s;
  __syncthreads();
  float mean = (red[0] + red[1] + red[2] + red[3]) * (1.0f / DIMD);

  float dx = x.x - mean, dy = x.y - mean, dz = x.z - mean, dw = x.w - mean;
  float sq = dx * dx + dy * dy + dz * dz + dw * dw;
  #pragma unroll
  for (int off = 1; off < 64; off <<= 1) sq += __shfl_xor(sq, off);
  if ((t & 63) == 0) red[4 + w] = sq;
  __syncthreads();
  float var = (red[4] + red[5] + red[6] + red[7]) * (1.0f / DIMD);
  float rs = rsqrtf(var + EPSF);

  float4 gg = *reinterpret_cast<const float4*>(g + t * 4);
  float4 bb = *reinterpret_cast<const float4*>(bt + t * 4);
  ushort4 o;
  o.x = f2bf(dx * rs * gg.x + bb.x);
  o.y = f2bf(dy * rs * gg.y + bb.y);
  o.z = f2bf(dz * rs * gg.z + bb.z);
  o.w = f2bf(dw * rs * gg.w + bb.w);
  *reinterpret_cast<ushort4*>(out + orow * DIMD + t * 4) = o;
}

// ---------------- transpose f32[R][C] -> bf16[C][R] (weights, tiny) ----------------
__global__ __launch_bounds__(256) void transpose_bf16(
    const float* __restrict__ in, unsigned short* __restrict__ out, int R, int C)
{
  __shared__ float t[32][33];
  int r0 = blockIdx.y * 32, c0 = blockIdx.x * 32;
  int tx = threadIdx.x, ty = threadIdx.y;
  #pragma unroll
  for (int p = 0; p < 4; p++)
    t[ty + p * 8][tx] = in[(long)(r0 + ty + p * 8) * C + c0 + tx];
  __syncthreads();
  #pragma unroll
  for (int p = 0; p < 4; p++)
    out[(long)(c0 + ty + p * 8) * R + r0 + tx] = f2bf(t[tx][ty + p * 8]);
}

// ---------------- bf16 MFMA GEMM (m97 structure): A[M][K] @ BT[N][K]^T ----------------
// 128x128 tile, BK=32, linear LDS, global_load_lds width=16 staging.
// ALL acc/fragment loops force-unrolled: runtime-indexed ext_vector arrays
// spill to scratch (round-2 bug: VGPR_Count=32, 15 GB scratch traffic).
__global__ __launch_bounds__(256) void gemm2(
    const unsigned short* __restrict__ A, const unsigned short* __restrict__ BT,
    int M, int N, int K, int mode,
    unsigned short* __restrict__ obf, float* __restrict__ of32,
    unsigned short* __restrict__ kbuf, unsigned short* __restrict__ vbuf)
{
  __shared__ unsigned short As[128 * 32];
  __shared__ unsigned short Bs[128 * 32];
  int tid = threadIdx.x, l = tid & 63, w = tid >> 6;
  int m0 = blockIdx.y * 128, n0 = blockIdx.x * 128;
  int wm = w >> 1, wn = w & 1;
  int lrow = l & 15, lk = (l >> 4) * 8;

  // staging map: wave w stages rows [w*16, w*16+16) and [(w+4)*16, ...): lane l -> row +(l>>2), col (l&3)*8
  int sr = l >> 2, scol = (l & 3) * 8;
  long am0 = m0 + w * 16 + sr, am1 = m0 + (w + 4) * 16 + sr;
  if (mode == 0) {
    am0 = (am0 >> 8) * KVLEN + N1 + (am0 & 255);
    am1 = (am1 >> 8) * KVLEN + N1 + (am1 & 255);
  }
  const unsigned short* gA0 = A + am0 * K + scol;
  const unsigned short* gA1 = A + am1 * K + scol;
  const unsigned short* gB0 = BT + (long)(n0 + w * 16 + sr) * K + scol;
  const unsigned short* gB1 = BT + (long)(n0 + (w + 4) * 16 + sr) * K + scol;
  unsigned short* lA0 = As + w * 512;
  unsigned short* lA1 = As + (w + 4) * 512;
  unsigned short* lB0 = Bs + w * 512;
  unsigned short* lB1 = Bs + (w + 4) * 512;

  f32x4 acc[4][4] = {};

  for (int k0 = 0; k0 < K; k0 += 32) {
    gload_lds16(gA0, lA0);
    gload_lds16(gA1, lA1);
    gload_lds16(gB0, lB0);
    gload_lds16(gB1, lB1);
    gA0 += 32; gA1 += 32; gB0 += 32; gB1 += 32;
    __syncthreads();  // drains vmcnt -> staged data visible
    bf16x8 af[4], bfr[4];
    #pragma unroll
    for (int i = 0; i < 4; i++)
      af[i] = *reinterpret_cast<bf16x8*>(&As[(wm * 64 + i * 16 + lrow) * 32 + lk]);
    #pragma unroll
    for (int j = 0; j < 4; j++)
      bfr[j] = *reinterpret_cast<bf16x8*>(&Bs[(wn * 64 + j * 16 + lrow) * 32 + lk]);
    #pragma unroll
    for (int i = 0; i < 4; i++)
      #pragma unroll
      for (int j = 0; j < 4; j++)
        acc[i][j] = __builtin_amdgcn_mfma_f32_16x16x32_bf16(af[i], bfr[j], acc[i][j], 0, 0, 0);
    __syncthreads();  // protect LDS before next-iter staging
  }

  #pragma unroll
  for (int i = 0; i < 4; i++)
    #pragma unroll
    for (int j = 0; j < 4; j++)
      #pragma unroll
      for (int r = 0; r < 4; r++) {
        int m = m0 + wm * 64 + i * 16 + (l >> 4) * 4 + r;
        int n = n0 + wn * 64 + j * 16 + (l & 15);
        float v = acc[i][j][r];
        if (mode == 0) {
          int b = m >> 8, qq = m & 255, h = n >> 6, d = n & 63;
          obf[(((long)(b * HEADS + h) * N2 + qq) << 6) + d] = f2bf(v);
        } else if (mode == 1) {
          int b = m / KVLEN, kk = m - b * KVLEN;  // 128 | KVLEN, tile is single-batch
          unsigned short* dst; int nn;
          if (n < DIMD) { dst = kbuf; nn = n; } else { dst = vbuf; nn = n - DIMD; }
          int h = nn >> 6, d = nn & 63;
          dst[(((long)(b * HEADS + h) * KVLEN + kk) << 6) + d] = f2bf(v);
        } else {
          of32[(long)m * N + n] = v;
        }
      }
}

// ---------------- V transpose: [b][h][kk][d] -> [b][h][d][kk], 64x64 LDS tiles ----------------
__global__ __launch_bounds__(256) void vtrans(
    const unsigned short* __restrict__ in, unsigned short* __restrict__ out)
{
  __shared__ unsigned short t[64][70];
  int bh = blockIdx.y, k0 = blockIdx.x * 64;
  int tid = threadIdx.x;
  const unsigned short* ip = in + ((long)bh * KVLEN + k0) * DHD;
  #pragma unroll
  for (int p = 0; p < 2; p++) {
    int eo = (tid + p * 256) * 8;
    int r = eo >> 6, c = eo & 63;
    *reinterpret_cast<bf16x8*>(&t[r][c]) =
        *reinterpret_cast<const bf16x8*>(ip + (long)r * DHD + c);
  }
  __syncthreads();
  unsigned short* op = out + (long)bh * DHD * KVLEN + k0;
  #pragma unroll
  for (int p = 0; p < 2; p++) {
    int eo = (tid + p * 256) * 8;
    int dd = eo >> 6, kc = eo & 63;
    ushort4 o0, o1;
    o0.x = t[kc + 0][dd]; o0.y = t[kc + 1][dd];
    o0.z = t[kc + 2][dd]; o0.w = t[kc + 3][dd];
    o1.x = t[kc + 4][dd]; o1.y = t[kc + 5][dd];
    o1.z = t[kc + 6][dd]; o1.w = t[kc + 7][dd];
    *reinterpret_cast<ushort4*>(op + (long)dd * KVLEN + kc) = o0;
    *reinterpret_cast<ushort4*>(op + (long)dd * KVLEN + kc + 4) = o1;
  }
}

// ---------------- flash attention: 1 block = (b,h, 64 q rows), 4 waves x 16 q rows ----------------
__global__ __launch_bounds__(256) void attn_kernel(
    const unsigned short* __restrict__ qb, const unsigned short* __restrict__ kb,
    const unsigned short* __restrict__ vtb, unsigned short* __restrict__ attn)
{
  __shared__ unsigned short Ks[64][72];
  __shared__ unsigned short Vs[64][72];
  __shared__ unsigned short Ps[4][16][72];
  int qt = blockIdx.x, bh = blockIdx.y;
  int tid = threadIdx.x, l = tid & 63, w = tid >> 6;
  int lrow = l & 15, lk = (l >> 4) * 8;

  const unsigned short* qp = qb + ((long)bh * N2 + qt * 64 + w * 16) * DHD;
  const unsigned short* kp = kb + (long)bh * KVLEN * DHD;
  const unsigned short* vp = vtb + (long)bh * DHD * KVLEN;

  bf16x8 qa[2];
  qa[0] = *reinterpret_cast<const bf16x8*>(qp + lrow * DHD + lk);
  qa[1] = *reinterpret_cast<const bf16x8*>(qp + lrow * DHD + 32 + lk);

  f32x4 O[4] = {};
  float mrow[4] = {-1e30f, -1e30f, -1e30f, -1e30f};
  float lsum[4] = {0.f, 0.f, 0.f, 0.f};

  for (int blk = 0; blk < KVLEN / 64; blk++) {
    __syncthreads();
    #pragma unroll
    for (int p = 0; p < 2; p++) {
      int eo = (tid + p * 256) * 8;
      int row = eo >> 6, col = eo & 63;
      *reinterpret_cast<bf16x8*>(&Ks[row][col]) =
          *reinterpret_cast<const bf16x8*>(kp + (long)(blk * 64 + row) * DHD + col);
      *reinterpret_cast<bf16x8*>(&Vs[row][col]) =
          *reinterpret_cast<const bf16x8*>(vp + (long)row * KVLEN + blk * 64 + col);
    }
    __syncthreads();

    f32x4 S[4];
    #pragma unroll
    for (int nt = 0; nt < 4; nt++) {
      f32x4 s = {};
      #pragma unroll
      for (int kt = 0; kt < 2; kt++) {
        bf16x8 bk = *reinterpret_cast<bf16x8*>(&Ks[nt * 16 + lrow][kt * 32 + lk]);
        s = __builtin_amdgcn_mfma_f32_16x16x32_bf16(qa[kt], bk, s, 0, 0, 0);
      }
      S[nt] = s * 0.125f;
    }

    float mx[4], rsum[4];
    #pragma unroll
    for (int r = 0; r < 4; r++) {
      float v = fmaxf(fmaxf(S[0][r], S[1][r]), fmaxf(S[2][r], S[3][r]));
      #pragma unroll
      for (int off = 1; off < 16; off <<= 1) v = fmaxf(v, __shfl_xor(v, off));
      mx[r] = v;
    }
    float fac[4];
    #pragma unroll
    for (int r = 0; r < 4; r++) {
      float mn = fmaxf(mrow[r], mx[r]);
      fac[r] = exp2f((mrow[r] - mn) * L2E);
      mrow[r] = mn;
      rsum[r] = 0.f;
    }
    #pragma unroll
    for (int nt = 0; nt < 4; nt++)
      #pragma unroll
      for (int r = 0; r < 4; r++) {
        float p = exp2f((S[nt][r] - mrow[r]) * L2E);
        rsum[r] += p;
        Ps[w][(l >> 4) * 4 + r][nt * 16 + lrow] = f2bf(p);
      }
    #pragma unroll
    for (int r = 0; r < 4; r++) {
      float v = rsum[r];
      #pragma unroll
      for (int off = 1; off < 16; off <<= 1) v += __shfl_xor(v, off);
      lsum[r] = lsum[r] * fac[r] + v;
    }
    #pragma unroll
    for (int dt = 0; dt < 4; dt++)
      #pragma unroll
      for (int r = 0; r < 4; r++) O[dt][r] *= fac[r];

    asm volatile("s_waitcnt lgkmcnt(0)" ::: "memory");
    bf16x8 pa[2];
    pa[0] = *reinterpret_cast<bf16x8*>(&Ps[w][lrow][lk]);
    pa[1] = *reinterpret_cast<bf16x8*>(&Ps[w][lrow][32 + lk]);
    #pragma unroll
    for (int dt = 0; dt < 4; dt++)
      #pragma unroll
      for (int kt = 0; kt < 2; kt++) {
        bf16x8 bv = *reinterpret_cast<bf16x8*>(&Vs[dt * 16 + lrow][kt * 32 + lk]);
        O[dt] = __builtin_amdgcn_mfma_f32_16x16x32_bf16(pa[kt], bv, O[dt], 0, 0, 0);
      }
  }

  int b = bh >> 4, h = bh & 15;
  #pragma unroll
  for (int dt = 0; dt < 4; dt++)
    #pragma unroll
    for (int r = 0; r < 4; r++) {
      int grow = b * N2 + qt * 64 + w * 16 + (l >> 4) * 4 + r;
      int col = h * DHD + dt * 16 + lrow;
      attn[(long)grow * DIMD + col] = f2bf(O[dt][r] / lsum[r]);
    }
}

// ---------------- launch ----------------
extern "C" void kernel_launch(void* const* d_in, const int* in_sizes, int n_in,
                              void* d_out, int out_size, void* d_ws, size_t ws_size,
                              hipStream_t stream) {
  const float* x    = (const float*)d_in[0];
  const float* lat  = (const float*)d_in[1];
  const float* g1   = (const float*)d_in[2];
  const float* b1   = (const float*)d_in[3];
  const float* g2   = (const float*)d_in[4];
  const float* b2   = (const float*)d_in[5];
  const float* Wq   = (const float*)d_in[6];
  const float* Wkv  = (const float*)d_in[7];
  const float* Wout = (const float*)d_in[8];
  float* out = (float*)d_out;

  char* ws = (char*)d_ws;
  size_t off = 0;
  auto alloc = [&](size_t bytes) -> void* {
    void* p = ws + off;
    off += (bytes + 255) & ~(size_t)255;
    return p;
  };
  unsigned short* kvin  = (unsigned short*)alloc((size_t)NB * KVLEN * DIMD * 2);
  unsigned short* WqT   = (unsigned short*)alloc((size_t)DIMD * DIMD * 2);
  unsigned short* WkvT  = (unsigned short*)alloc((size_t)2 * DIMD * DIMD * 2);
  unsigned short* WoutT = (unsigned short*)alloc((size_t)DIMD * DIMD * 2);
  unsigned short* qbuf  = (unsigned short*)alloc((size_t)NB * N2 * DIMD * 2);
  unsigned short* kbuf  = (unsigned short*)alloc((size_t)NB * HEADS * KVLEN * DHD * 2);
  unsigned short* vbuf  = (unsigned short*)alloc((size_t)NB * HEADS * KVLEN * DHD * 2);
  unsigned short* attn  = (unsigned short*)alloc((size_t)NB * N2 * DIMD * 2);
  if (off > ws_size) return;
  // vtbuf aliases kvin (dead after KV GEMM; sizes match exactly)
  unsigned short* vtbuf = kvin;

  // weights -> bf16 [N][K]
  transpose_bf16<<<dim3(DIMD / 32, DIMD / 32), dim3(32, 8), 0, stream>>>(Wq, WqT, DIMD, DIMD);
  transpose_bf16<<<dim3(2 * DIMD / 32, DIMD / 32), dim3(32, 8), 0, stream>>>(Wkv, WkvT, DIMD, 2 * DIMD);
  transpose_bf16<<<dim3(DIMD / 32, DIMD / 32), dim3(32, 8), 0, stream>>>(Wout, WoutT, DIMD, DIMD);

  // layernorms into combined kv-input buffer
  ln_kernel<<<NB * N1, 256, 0, stream>>>(x, g1, b1, kvin, N1, 0);
  ln_kernel<<<NB * N2, 256, 0, stream>>>(lat, g2, b2, kvin, N2, N1);

  // Q = ln @ Wq   (M=2048, N=1024)
  gemm2<<<dim3(8, 16), 256, 0, stream>>>(kvin, WqT, NB * N2, DIMD, DIMD, 0,
                                         qbuf, nullptr, nullptr, nullptr);
  // KV = [xn;ln] @ Wkv  (M=34816, N=2048) -> K,V natural [b][h][kk][d]
  gemm2<<<dim3(16, 272), 256, 0, stream>>>(kvin, WkvT, NB * KVLEN, 2 * DIMD, DIMD, 1,
                                           nullptr, nullptr, kbuf, vbuf);
  // V -> V^T  [b][h][d][kk]
  vtrans<<<dim3(KVLEN / 64, NB * HEADS), 256, 0, stream>>>(vbuf, vtbuf);
  // attention
  attn_kernel<<<dim3(4, NB * HEADS), 256, 0, stream>>>(qbuf, kbuf, vtbuf, attn);
  // out = attn @ Wout  (M=2048, N=1024) -> f32
  gemm2<<<dim3(8, 16), 256, 0, stream>>>(attn, WoutT, NB * N2, DIMD, DIMD, 2,
                                         nullptr, out, nullptr, nullptr);
}

// Round 5
// 645.542 us; speedup vs baseline: 5.8552x; 1.0987x over previous
//
#include <hip/hip_runtime.h>
#include <hip/hip_bf16.h>

#define NB 8
#define N1 4096
#define N2 256
#define DIMD 1024
#define HEADS 16
#define DHD 64
#define KVLEN 4352
#define EPSF 1e-5f
#define L2E 1.44269504088896340736f

typedef __bf16 bf16x8 __attribute__((ext_vector_type(8)));
typedef float f32x4 __attribute__((ext_vector_type(4)));

__device__ __forceinline__ unsigned short f2bf(float f) {
  union { float f; unsigned int u; } v; v.f = f;
  return (unsigned short)((v.u + 0x7FFFu + ((v.u >> 16) & 1u)) >> 16);
}

__device__ __forceinline__ void gload_lds16(const void* g, void* l) {
  __builtin_amdgcn_global_load_lds(
      (const __attribute__((address_space(1))) void*)g,
      (__attribute__((address_space(3))) void*)l, 16, 0, 0);
}

// ---------------- LayerNorm: f32 row -> bf16 row into combined kv-input ----------------
__global__ __launch_bounds__(256) void ln_kernel(
    const float* __restrict__ in, const float* __restrict__ g, const float* __restrict__ bt,
    unsigned short* __restrict__ out, int rows_per_b, int out_off)
{
  int row = blockIdx.x;
  int b = row / rows_per_b;
  int r = row - b * rows_per_b;
  long orow = (long)b * KVLEN + out_off + r;
  const float* rp = in + (long)row * DIMD;
  int t = threadIdx.x;

  float4 x = *reinterpret_cast<const float4*>(rp + t * 4);
  float s = x.x + x.y + x.z + x.w;
  #pragma unroll
  for (int off = 1; off < 64; off <<= 1) s += __shfl_xor(s, off);
  __shared__ float red[8];
  int w = t >> 6;
  if ((t & 63) == 0) red[w] = s;
  __syncthreads();
  float mean = (red[0] + red[1] + red[2] + red[3]) * (1.0f / DIMD);

  float dx = x.x - mean, dy = x.y - mean, dz = x.z - mean, dw = x.w - mean;
  float sq = dx * dx + dy * dy + dz * dz + dw * dw;
  #pragma unroll
  for (int off = 1; off < 64; off <<= 1) sq += __shfl_xor(sq, off);
  if ((t & 63) == 0) red[4 + w] = sq;
  __syncthreads();
  float var = (red[4] + red[5] + red[6] + red[7]) * (1.0f / DIMD);
  float rs = rsqrtf(var + EPSF);

  float4 gg = *reinterpret_cast<const float4*>(g + t * 4);
  float4 bb = *reinterpret_cast<const float4*>(bt + t * 4);
  ushort4 o;
  o.x = f2bf(dx * rs * gg.x + bb.x);
  o.y = f2bf(dy * rs * gg.y + bb.y);
  o.z = f2bf(dz * rs * gg.z + bb.z);
  o.w = f2bf(dw * rs * gg.w + bb.w);
  *reinterpret_cast<ushort4*>(out + orow * DIMD + t * 4) = o;
}

// ---------------- transpose f32[R][C] -> bf16[C][R] (weights, tiny) ----------------
__global__ __launch_bounds__(256) void transpose_bf16(
    const float* __restrict__ in, unsigned short* __restrict__ out, int R, int C)
{
  __shared__ float t[32][33];
  int r0 = blockIdx.y * 32, c0 = blockIdx.x * 32;
  int tx = threadIdx.x, ty = threadIdx.y;
  #pragma unroll
  for (int p = 0; p < 4; p++)
    t[ty + p * 8][tx] = in[(long)(r0 + ty + p * 8) * C + c0 + tx];
  __syncthreads();
  #pragma unroll
  for (int p = 0; p < 4; p++)
    out[(long)(c0 + ty + p * 8) * R + r0 + tx] = f2bf(t[tx][ty + p * 8]);
}

// ================= 8-phase 256x256 KV GEMM =================
// A[34816][1024] bf16 (kvin), BT[2048][1024] bf16 (WkvT).
// K cols (n<1024) -> kbuf [b][h][kk][d]; V cols -> vtbuf [b][h][d][kk] via LDS bounce.
// 8 waves (512 thr): wm=w>>2 (2 M-halves of 128), wn=w&3 (4 N-bands of 64).
// LDS 128KB: Abuf[2][256][64] | Bbuf[2][256][64], XOR-swizzle slot^=(row&7) via
// linear dest + inverse-swizzled global source (gload_lds writes linearly).
// Schedule per iter (tiles t0=2i buf0, t1=2i+1 buf1):
//  P1: LDA(b0)+LDB(b0,0), stage B0(t1)->b1 | P2: LDB(b0,1), stage B1(t1)->b1
//  P3: LDB(b0,2), stage A0(t2)->b0        | P4: LDB(b0,3), stage A1(t2)->b0, vmcnt(4)
//  P5-P8 mirror on buf1 with stages B0/B1(t2)->b0, A0/A1(t3)->b1, vmcnt(4)@P8.
// vmcnt(4) (FIFO) guarantees the next tile fully landed; all restages hit regions
// whose last ds_read completed >=1 phase earlier (A consumed at P1/P5, B through P4/P8).

#define BARRIER8() { __builtin_amdgcn_sched_barrier(0); __builtin_amdgcn_s_barrier(); __builtin_amdgcn_sched_barrier(0); }
#define VMW4() { asm volatile("s_waitcnt vmcnt(4)" ::: "memory"); __builtin_amdgcn_sched_barrier(0); }

#define STG1(KIND, BUF, HALF, TILE, Q) \
  gload_lds16((KIND ? BT : A) + \
      (long)(((KIND) ? n0 : m0) + (HALF)*128 + w*16 + (Q)*8 + srow8) * 1024 + (TILE)*64 + sslot*8, \
      lds + (KIND)*32768 + (BUF)*16384 + ((HALF)*128 + w*16 + (Q)*8)*64)
#define STAGE8(KIND, BUF, HALF, TILE) { STG1(KIND,BUF,HALF,TILE,0); STG1(KIND,BUF,HALF,TILE,1); }

#define LDA8(BUF) { _Pragma("unroll") for (int mt = 0; mt < 8; mt++) { \
    int ar = wm*128 + mt*16 + lrow; \
    af[mt][0] = *(const bf16x8*)&lds[(BUF)*16384 + ar*64 + ((l4) ^ (ar&7))*8]; \
    af[mt][1] = *(const bf16x8*)&lds[(BUF)*16384 + ar*64 + ((4+l4) ^ (ar&7))*8]; } }

#define LDB8(BUF, NT) { int br = wn*64 + (NT)*16 + lrow; \
    bf0 = *(const bf16x8*)&lds[32768 + (BUF)*16384 + br*64 + ((l4) ^ (br&7))*8]; \
    bf1 = *(const bf16x8*)&lds[32768 + (BUF)*16384 + br*64 + ((4+l4) ^ (br&7))*8]; }

#define MM8(NT) { __builtin_amdgcn_s_setprio(1); \
    _Pragma("unroll") for (int mt = 0; mt < 8; mt++) { \
      acc[mt][NT] = __builtin_amdgcn_mfma_f32_16x16x32_bf16(af[mt][0], bf0, acc[mt][NT], 0, 0, 0); \
      acc[mt][NT] = __builtin_amdgcn_mfma_f32_16x16x32_bf16(af[mt][1], bf1, acc[mt][NT], 0, 0, 0); } \
    __builtin_amdgcn_s_setprio(0); }

__global__ __launch_bounds__(512, 1) void gemm8(
    const unsigned short* __restrict__ A, const unsigned short* __restrict__ BT,
    unsigned short* __restrict__ kbuf, unsigned short* __restrict__ vtbuf)
{
  __shared__ unsigned short lds[65536];  // 128 KB
  int tid = threadIdx.x, l = tid & 63, w = tid >> 6;
  int wm = w >> 2, wn = w & 3;
  int lrow = l & 15, l4 = l >> 4;
  int bx = blockIdx.x, by = blockIdx.y;
  int m0 = by * 256, n0 = bx * 256;
  int srow8 = l >> 3;
  int sslot = (l & 7) ^ srow8;

  f32x4 acc[8][4] = {};
  bf16x8 af[8][2];
  bf16x8 bf0, bf1;

  // prologue: tile0 full -> buf0; tile1 A-halves -> buf1 (12 loads/wave)
  STAGE8(0, 0, 0, 0); STAGE8(0, 0, 1, 0);
  STAGE8(1, 0, 0, 0); STAGE8(1, 0, 1, 0);
  STAGE8(0, 1, 0, 1); STAGE8(0, 1, 1, 1);
  VMW4(); BARRIER8();

  for (int it = 0; it < 8; ++it) {
    int t1 = 2 * it + 1;
    int t2 = 2 * it + 2; if (t2 > 15) t2 = 15;  // clamped stages hit dead regions only
    int t3 = 2 * it + 3; if (t3 > 15) t3 = 15;
    // P1
    LDA8(0); LDB8(0, 0);
    STAGE8(1, 1, 0, t1);
    BARRIER8(); MM8(0); BARRIER8();
    // P2
    LDB8(0, 1);
    STAGE8(1, 1, 1, t1);
    BARRIER8(); MM8(1); BARRIER8();
    // P3
    LDB8(0, 2);
    STAGE8(0, 0, 0, t2);
    BARRIER8(); MM8(2); BARRIER8();
    // P4
    LDB8(0, 3);
    STAGE8(0, 0, 1, t2);
    BARRIER8(); MM8(3); VMW4(); BARRIER8();
    // P5
    LDA8(1); LDB8(1, 0);
    STAGE8(1, 0, 0, t2);
    BARRIER8(); MM8(0); BARRIER8();
    // P6
    LDB8(1, 1);
    STAGE8(1, 0, 1, t2);
    BARRIER8(); MM8(1); BARRIER8();
    // P7
    LDB8(1, 2);
    STAGE8(0, 1, 0, t3);
    BARRIER8(); MM8(2); BARRIER8();
    // P8
    LDB8(1, 3);
    STAGE8(0, 1, 1, t3);
    BARRIER8(); MM8(3); VMW4(); BARRIER8();
  }

  __syncthreads();  // drain everything; LDS now reusable

  int b = by / 17;                 // KVLEN/256 = 17 tiles per batch
  int kk0 = m0 - b * KVLEN;

  if (n0 < DIMD) {
    // K columns: direct [b][h][kk][d] stores
    #pragma unroll
    for (int mt = 0; mt < 8; mt++)
      #pragma unroll
      for (int nt = 0; nt < 4; nt++)
        #pragma unroll
        for (int r = 0; r < 4; r++) {
          int kk = kk0 + wm * 128 + mt * 16 + l4 * 4 + r;
          int h = bx * 4 + wn;
          int d = nt * 16 + lrow;
          kbuf[(((long)(b * HEADS + h) * KVLEN + kk) << 6) + d] = f2bf(acc[mt][nt][r]);
        }
  } else {
    // V columns: bounce 256x256 tile through LDS (transposed, XOR-swizzled), then
    // write vtbuf [b][h][d][kk] with coalesced 16B row stores.
    #pragma unroll
    for (int mt = 0; mt < 8; mt++)
      #pragma unroll
      for (int nt = 0; nt < 4; nt++)
        #pragma unroll
        for (int r = 0; r < 4; r++) {
          int nl = wn * 64 + nt * 16 + lrow;
          int ml = wm * 128 + mt * 16 + l4 * 4 + r;
          lds[nl * 256 + (ml ^ ((nl & 15) << 4))] = f2bf(acc[mt][nt][r]);
        }
    __syncthreads();
    int nl = tid >> 1, mc = (tid & 1) * 128;
    int h = bx * 4 + (nl >> 6) - HEADS;
    int d = nl & 63;
    unsigned short* op = vtbuf + ((long)(b * HEADS + h) * DHD + d) * KVLEN + kk0 + mc;
    #pragma unroll
    for (int j = 0; j < 16; j++) {
      bf16x8 v = *(const bf16x8*)&lds[nl * 256 + ((mc + j * 8) ^ ((nl & 15) << 4))];
      *(bf16x8*)(op + j * 8) = v;
    }
  }
}

// ---------------- small GEMM: 128x64 tile, BK=32 (Q and OUT projections) ----------------
// mode 0: A rows remapped to latent rows of kvin; out -> qbuf [b][h][q][d] bf16, PRE-SCALED 0.125
// mode 2: out -> of32 [M][1024] f32
__global__ __launch_bounds__(256) void gemm3(
    const unsigned short* __restrict__ A, const unsigned short* __restrict__ BT,
    int mode, unsigned short* __restrict__ obf, float* __restrict__ of32)
{
  __shared__ unsigned short As[128 * 32];
  __shared__ unsigned short Bs[64 * 32];
  const int K = DIMD;
  int tid = threadIdx.x, l = tid & 63, w = tid >> 6;
  int m0 = blockIdx.y * 128, n0 = blockIdx.x * 64;
  int lrow = l & 15, lk = (l >> 4) * 8;

  int sr = l >> 2, scol = (l & 3) * 8;
  long am0 = m0 + w * 16 + sr, am1 = m0 + (w + 4) * 16 + sr;
  if (mode == 0) {
    am0 = (am0 >> 8) * KVLEN + N1 + (am0 & 255);
    am1 = (am1 >> 8) * KVLEN + N1 + (am1 & 255);
  }
  const unsigned short* gA0 = A + am0 * K + scol;
  const unsigned short* gA1 = A + am1 * K + scol;
  const unsigned short* gB = BT + (long)(n0 + w * 16 + sr) * K + scol;
  unsigned short* lA0 = As + w * 512;
  unsigned short* lA1 = As + (w + 4) * 512;
  unsigned short* lB = Bs + w * 512;

  f32x4 acc[2][4] = {};

  for (int k0 = 0; k0 < K; k0 += 32) {
    gload_lds16(gA0, lA0);
    gload_lds16(gA1, lA1);
    gload_lds16(gB, lB);
    gA0 += 32; gA1 += 32; gB += 32;
    __syncthreads();
    bf16x8 af[2], bfr[4];
    #pragma unroll
    for (int i = 0; i < 2; i++)
      af[i] = *reinterpret_cast<bf16x8*>(&As[(w * 32 + i * 16 + lrow) * 32 + lk]);
    #pragma unroll
    for (int j = 0; j < 4; j++)
      bfr[j] = *reinterpret_cast<bf16x8*>(&Bs[(j * 16 + lrow) * 32 + lk]);
    #pragma unroll
    for (int i = 0; i < 2; i++)
      #pragma unroll
      for (int j = 0; j < 4; j++)
        acc[i][j] = __builtin_amdgcn_mfma_f32_16x16x32_bf16(af[i], bfr[j], acc[i][j], 0, 0, 0);
    __syncthreads();
  }

  #pragma unroll
  for (int i = 0; i < 2; i++)
    #pragma unroll
    for (int j = 0; j < 4; j++)
      #pragma unroll
      for (int r = 0; r < 4; r++) {
        int m = m0 + w * 32 + i * 16 + (l >> 4) * 4 + r;
        int n = n0 + j * 16 + lrow;
        float v = acc[i][j][r];
        if (mode == 0) {
          int b = m >> 8, qq = m & 255, h = n >> 6, d = n & 63;
          obf[(((long)(b * HEADS + h) * N2 + qq) << 6) + d] = f2bf(v * 0.125f);
        } else {
          of32[(long)m * DIMD + n] = v;
        }
      }
}

// ---------------- flash attention: 1 block = (b,h, 64 q rows), 4 waves x 16 q rows ----------------
__global__ __launch_bounds__(256) void attn_kernel(
    const unsigned short* __restrict__ qb, const unsigned short* __restrict__ kb,
    const unsigned short* __restrict__ vtb, unsigned short* __restrict__ attn)
{
  __shared__ unsigned short Ks[64][72];
  __shared__ unsigned short Vs[64][72];
  __shared__ unsigned short Ps[4][16][72];
  int qt = blockIdx.x, bh = blockIdx.y;
  int tid = threadIdx.x, l = tid & 63, w = tid >> 6;
  int lrow = l & 15, lk = (l >> 4) * 8;

  const unsigned short* qp = qb + ((long)bh * N2 + qt * 64 + w * 16) * DHD;
  const unsigned short* kp = kb + (long)bh * KVLEN * DHD;
  const unsigned short* vp = vtb + (long)bh * DHD * KVLEN;

  bf16x8 qa[2];
  qa[0] = *reinterpret_cast<const bf16x8*>(qp + lrow * DHD + lk);
  qa[1] = *reinterpret_cast<const bf16x8*>(qp + lrow * DHD + 32 + lk);

  f32x4 O[4] = {};
  float mrow[4] = {-1e30f, -1e30f, -1e30f, -1e30f};
  float lsum[4] = {0.f, 0.f, 0.f, 0.f};

  for (int blk = 0; blk < KVLEN / 64; blk++) {
    __syncthreads();
    #pragma unroll
    for (int p = 0; p < 2; p++) {
      int eo = (tid + p * 256) * 8;
      int row = eo >> 6, col = eo & 63;
      *reinterpret_cast<bf16x8*>(&Ks[row][col]) =
          *reinterpret_cast<const bf16x8*>(kp + (long)(blk * 64 + row) * DHD + col);
      *reinterpret_cast<bf16x8*>(&Vs[row][col]) =
          *reinterpret_cast<const bf16x8*>(vp + (long)row * KVLEN + blk * 64 + col);
    }
    __syncthreads();

    f32x4 S[4];
    __builtin_amdgcn_s_setprio(1);
    #pragma unroll
    for (int nt = 0; nt < 4; nt++) {
      f32x4 s = {};
      #pragma unroll
      for (int kt = 0; kt < 2; kt++) {
        bf16x8 bk = *reinterpret_cast<bf16x8*>(&Ks[nt * 16 + lrow][kt * 32 + lk]);
        s = __builtin_amdgcn_mfma_f32_16x16x32_bf16(qa[kt], bk, s, 0, 0, 0);
      }
      S[nt] = s;  // Q pre-scaled by 0.125 at Q-GEMM epilogue
    }
    __builtin_amdgcn_s_setprio(0);

    float mx[4], rsum[4];
    #pragma unroll
    for (int r = 0; r < 4; r++) {
      float v = fmaxf(fmaxf(S[0][r], S[1][r]), fmaxf(S[2][r], S[3][r]));
      #pragma unroll
      for (int off = 1; off < 16; off <<= 1) v = fmaxf(v, __shfl_xor(v, off));
      mx[r] = v;
    }
    float fac[4];
    #pragma unroll
    for (int r = 0; r < 4; r++) {
      float mn = fmaxf(mrow[r], mx[r]);
      fac[r] = exp2f((mrow[r] - mn) * L2E);
      mrow[r] = mn;
      rsum[r] = 0.f;
    }
    #pragma unroll
    for (int nt = 0; nt < 4; nt++)
      #pragma unroll
      for (int r = 0; r < 4; r++) {
        float p = exp2f((S[nt][r] - mrow[r]) * L2E);
        rsum[r] += p;
        Ps[w][(l >> 4) * 4 + r][nt * 16 + lrow] = f2bf(p);
      }
    #pragma unroll
    for (int r = 0; r < 4; r++) {
      float v = rsum[r];
      #pragma unroll
      for (int off = 1; off < 16; off <<= 1) v += __shfl_xor(v, off);
      lsum[r] = lsum[r] * fac[r] + v;
    }
    #pragma unroll
    for (int dt = 0; dt < 4; dt++)
      #pragma unroll
      for (int r = 0; r < 4; r++) O[dt][r] *= fac[r];

    asm volatile("s_waitcnt lgkmcnt(0)" ::: "memory");
    bf16x8 pa[2];
    pa[0] = *reinterpret_cast<bf16x8*>(&Ps[w][lrow][lk]);
    pa[1] = *reinterpret_cast<bf16x8*>(&Ps[w][lrow][32 + lk]);
    __builtin_amdgcn_s_setprio(1);
    #pragma unroll
    for (int dt = 0; dt < 4; dt++)
      #pragma unroll
      for (int kt = 0; kt < 2; kt++) {
        bf16x8 bv = *reinterpret_cast<bf16x8*>(&Vs[dt * 16 + lrow][kt * 32 + lk]);
        O[dt] = __builtin_amdgcn_mfma_f32_16x16x32_bf16(pa[kt], bv, O[dt], 0, 0, 0);
      }
    __builtin_amdgcn_s_setprio(0);
  }

  int b = bh >> 4, h = bh & 15;
  #pragma unroll
  for (int dt = 0; dt < 4; dt++)
    #pragma unroll
    for (int r = 0; r < 4; r++) {
      int grow = b * N2 + qt * 64 + w * 16 + (l >> 4) * 4 + r;
      int col = h * DHD + dt * 16 + lrow;
      attn[(long)grow * DIMD + col] = f2bf(O[dt][r] / lsum[r]);
    }
}

// ---------------- launch ----------------
extern "C" void kernel_launch(void* const* d_in, const int* in_sizes, int n_in,
                              void* d_out, int out_size, void* d_ws, size_t ws_size,
                              hipStream_t stream) {
  const float* x    = (const float*)d_in[0];
  const float* lat  = (const float*)d_in[1];
  const float* g1   = (const float*)d_in[2];
  const float* b1   = (const float*)d_in[3];
  const float* g2   = (const float*)d_in[4];
  const float* b2   = (const float*)d_in[5];
  const float* Wq   = (const float*)d_in[6];
  const float* Wkv  = (const float*)d_in[7];
  const float* Wout = (const float*)d_in[8];
  float* out = (float*)d_out;

  char* ws = (char*)d_ws;
  size_t off = 0;
  auto alloc = [&](size_t bytes) -> void* {
    void* p = ws + off;
    off += (bytes + 255) & ~(size_t)255;
    return p;
  };
  unsigned short* kvin  = (unsigned short*)alloc((size_t)NB * KVLEN * DIMD * 2);
  unsigned short* WqT   = (unsigned short*)alloc((size_t)DIMD * DIMD * 2);
  unsigned short* WkvT  = (unsigned short*)alloc((size_t)2 * DIMD * DIMD * 2);
  unsigned short* WoutT = (unsigned short*)alloc((size_t)DIMD * DIMD * 2);
  unsigned short* qbuf  = (unsigned short*)alloc((size_t)NB * N2 * DIMD * 2);
  unsigned short* kbuf  = (unsigned short*)alloc((size_t)NB * HEADS * KVLEN * DHD * 2);
  unsigned short* vtbuf = (unsigned short*)alloc((size_t)NB * HEADS * KVLEN * DHD * 2);
  unsigned short* attn  = (unsigned short*)alloc((size_t)NB * N2 * DIMD * 2);
  if (off > ws_size) return;

  // weights -> bf16 [N][K]
  transpose_bf16<<<dim3(DIMD / 32, DIMD / 32), dim3(32, 8), 0, stream>>>(Wq, WqT, DIMD, DIMD);
  transpose_bf16<<<dim3(2 * DIMD / 32, DIMD / 32), dim3(32, 8), 0, stream>>>(Wkv, WkvT, DIMD, 2 * DIMD);
  transpose_bf16<<<dim3(DIMD / 32, DIMD / 32), dim3(32, 8), 0, stream>>>(Wout, WoutT, DIMD, DIMD);

  // layernorms into combined kv-input buffer
  ln_kernel<<<NB * N1, 256, 0, stream>>>(x, g1, b1, kvin, N1, 0);
  ln_kernel<<<NB * N2, 256, 0, stream>>>(lat, g2, b2, kvin, N2, N1);

  // Q = ln @ Wq (M=2048, N=1024), pre-scaled 0.125
  gemm3<<<dim3(16, 16), 256, 0, stream>>>(kvin, WqT, 0, qbuf, nullptr);
  // KV = [xn;ln] @ Wkv (M=34816, N=2048): K -> kbuf, V -> vtbuf (transposed in-kernel)
  gemm8<<<dim3(8, 136), 512, 0, stream>>>(kvin, WkvT, kbuf, vtbuf);
  // attention
  attn_kernel<<<dim3(4, NB * HEADS), 256, 0, stream>>>(qbuf, kbuf, vtbuf, attn);
  // out = attn @ Wout (M=2048, N=1024) -> f32
  gemm3<<<dim3(16, 16), 256, 0, stream>>>(attn, WoutT, 2, nullptr, out);
}

// Round 7
// 644.778 us; speedup vs baseline: 5.8621x; 1.0012x over previous
//
#include <hip/hip_runtime.h>
#include <hip/hip_bf16.h>

#define NB 8
#define N1 4096
#define N2 256
#define DIMD 1024
#define HEADS 16
#define DHD 64
#define KVLEN 4352
#define EPSF 1e-5f
#define L2E 1.44269504088896340736f

typedef __bf16 bf16x8 __attribute__((ext_vector_type(8)));
typedef float f32x4 __attribute__((ext_vector_type(4)));

__device__ __forceinline__ unsigned short f2bf(float f) {
  union { float f; unsigned int u; } v; v.f = f;
  return (unsigned short)((v.u + 0x7FFFu + ((v.u >> 16) & 1u)) >> 16);
}

__device__ __forceinline__ void gload_lds16(const void* g, void* l) {
  __builtin_amdgcn_global_load_lds(
      (const __attribute__((address_space(1))) void*)g,
      (__attribute__((address_space(3))) void*)l, 16, 0, 0);
}

// ---------------- LayerNorm: f32 row -> bf16 row into combined kv-input ----------------
__global__ __launch_bounds__(256) void ln_kernel(
    const float* __restrict__ in, const float* __restrict__ g, const float* __restrict__ bt,
    unsigned short* __restrict__ out, int rows_per_b, int out_off)
{
  int row = blockIdx.x;
  int b = row / rows_per_b;
  int r = row - b * rows_per_b;
  long orow = (long)b * KVLEN + out_off + r;
  const float* rp = in + (long)row * DIMD;
  int t = threadIdx.x;

  float4 x = *reinterpret_cast<const float4*>(rp + t * 4);
  float s = x.x + x.y + x.z + x.w;
  #pragma unroll
  for (int off = 1; off < 64; off <<= 1) s += __shfl_xor(s, off);
  __shared__ float red[8];
  int w = t >> 6;
  if ((t & 63) == 0) red[w] = s;
  __syncthreads();
  float mean = (red[0] + red[1] + red[2] + red[3]) * (1.0f / DIMD);

  float dx = x.x - mean, dy = x.y - mean, dz = x.z - mean, dw = x.w - mean;
  float sq = dx * dx + dy * dy + dz * dz + dw * dw;
  #pragma unroll
  for (int off = 1; off < 64; off <<= 1) sq += __shfl_xor(sq, off);
  if ((t & 63) == 0) red[4 + w] = sq;
  __syncthreads();
  float var = (red[4] + red[5] + red[6] + red[7]) * (1.0f / DIMD);
  float rs = rsqrtf(var + EPSF);

  float4 gg = *reinterpret_cast<const float4*>(g + t * 4);
  float4 bb = *reinterpret_cast<const float4*>(bt + t * 4);
  ushort4 o;
  o.x = f2bf(dx * rs * gg.x + bb.x);
  o.y = f2bf(dy * rs * gg.y + bb.y);
  o.z = f2bf(dz * rs * gg.z + bb.z);
  o.w = f2bf(dw * rs * gg.w + bb.w);
  *reinterpret_cast<ushort4*>(out + orow * DIMD + t * 4) = o;
}

// ---------------- transpose f32[R][C] -> bf16[C][R] (weights, tiny) ----------------
__global__ __launch_bounds__(256) void transpose_bf16(
    const float* __restrict__ in, unsigned short* __restrict__ out, int R, int C)
{
  __shared__ float t[32][33];
  int r0 = blockIdx.y * 32, c0 = blockIdx.x * 32;
  int tx = threadIdx.x, ty = threadIdx.y;
  #pragma unroll
  for (int p = 0; p < 4; p++)
    t[ty + p * 8][tx] = in[(long)(r0 + ty + p * 8) * C + c0 + tx];
  __syncthreads();
  #pragma unroll
  for (int p = 0; p < 4; p++)
    out[(long)(c0 + ty + p * 8) * R + r0 + tx] = f2bf(t[tx][ty + p * 8]);
}

// ================= 8-phase 256x256 KV GEMM =================
// Schedule identical to R5 (stage slots, vmcnt(4)@P4/P8, prologue). Changes vs R5:
//  - reads spread: P1 = B all (8) + A mt0-3 (8); P2 = A mt4-7 (8); P3/P4 none.
//    (A fully read by P2-end, so A-restage at P3/P4 stays >=1 barrier behind.)
//  - raw s_barrier, NO sched_barrier pinning (m141 anti-pattern removed).
//  - K epilogue via LDS bounce -> coalesced 16B stores.

#define BAR8() __builtin_amdgcn_s_barrier()
#define LGKM0() asm volatile("s_waitcnt lgkmcnt(0)" ::: "memory")
#define VMW4() { asm volatile("s_waitcnt vmcnt(4)" ::: "memory"); __builtin_amdgcn_sched_barrier(0); }

#define STG1(KIND, BUF, HALF, TILE, Q) \
  gload_lds16((KIND ? BT : A) + \
      (long)(((KIND) ? n0 : m0) + (HALF)*128 + w*16 + (Q)*8 + srow8) * 1024 + (TILE)*64 + sslot*8, \
      lds + (KIND)*32768 + (BUF)*16384 + ((HALF)*128 + w*16 + (Q)*8)*64)
#define STAGE8(KIND, BUF, HALF, TILE) { STG1(KIND,BUF,HALF,TILE,0); STG1(KIND,BUF,HALF,TILE,1); }

#define LDB_ALL(BUF) { _Pragma("unroll") \
  for (int nt = 0; nt < 4; nt++) { int br = wn*64 + nt*16 + lrow; \
    bfr[nt][0] = *(const bf16x8*)&lds[32768 + (BUF)*16384 + br*64 + ((l4) ^ (br&7))*8]; \
    bfr[nt][1] = *(const bf16x8*)&lds[32768 + (BUF)*16384 + br*64 + ((4+l4) ^ (br&7))*8]; } }

#define LDA_H(BUF, AF, MT0) { _Pragma("unroll") \
  for (int q = 0; q < 4; q++) { int ar = wm*128 + ((MT0)+q)*16 + lrow; \
    AF[q][0] = *(const bf16x8*)&lds[(BUF)*16384 + ar*64 + ((l4) ^ (ar&7))*8]; \
    AF[q][1] = *(const bf16x8*)&lds[(BUF)*16384 + ar*64 + ((4+l4) ^ (ar&7))*8]; } }

#define MMP(AF, QB, MB) { __builtin_amdgcn_s_setprio(1); \
  _Pragma("unroll") for (int q = 0; q < 2; q++) \
    _Pragma("unroll") for (int nt = 0; nt < 4; nt++) { \
      acc[(MB)+q][nt] = __builtin_amdgcn_mfma_f32_16x16x32_bf16(AF[(QB)+q][0], bfr[nt][0], acc[(MB)+q][nt], 0, 0, 0); \
      acc[(MB)+q][nt] = __builtin_amdgcn_mfma_f32_16x16x32_bf16(AF[(QB)+q][1], bfr[nt][1], acc[(MB)+q][nt], 0, 0, 0); } \
  __builtin_amdgcn_s_setprio(0); }

__global__ __launch_bounds__(512, 1) void gemm8(
    const unsigned short* __restrict__ A, const unsigned short* __restrict__ BT,
    unsigned short* __restrict__ kbuf, unsigned short* __restrict__ vtbuf)
{
  __shared__ unsigned short lds[65536];  // 128 KB
  int tid = threadIdx.x, l = tid & 63, w = tid >> 6;
  int wm = w >> 2, wn = w & 3;
  int lrow = l & 15, l4 = l >> 4;
  int bx = blockIdx.x, by = blockIdx.y;
  int m0 = by * 256, n0 = bx * 256;
  int srow8 = l >> 3;
  int sslot = (l & 7) ^ srow8;

  f32x4 acc[8][4] = {};
  bf16x8 afA[4][2], afB[4][2];
  bf16x8 bfr[4][2];

  // prologue: tile0 full -> buf0; tile1 A-halves -> buf1 (12 loads/wave)
  STAGE8(0, 0, 0, 0); STAGE8(0, 0, 1, 0);
  STAGE8(1, 0, 0, 0); STAGE8(1, 0, 1, 0);
  STAGE8(0, 1, 0, 1); STAGE8(0, 1, 1, 1);
  VMW4(); BAR8();

  for (int it = 0; it < 8; ++it) {
    int t1 = 2 * it + 1;
    int t2 = 2 * it + 2; if (t2 > 15) t2 = 15;  // clamped stages hit dead regions only
    int t3 = 2 * it + 3; if (t3 > 15) t3 = 15;
    // P1
    LDB_ALL(0); LDA_H(0, afA, 0);
    STAGE8(1, 1, 0, t1);
    BAR8(); LGKM0(); MMP(afA, 0, 0); BAR8();
    // P2
    LDA_H(0, afB, 4);
    STAGE8(1, 1, 1, t1);
    BAR8(); LGKM0(); MMP(afA, 2, 2); BAR8();
    // P3
    STAGE8(0, 0, 0, t2);
    BAR8(); MMP(afB, 0, 4); BAR8();
    // P4
    STAGE8(0, 0, 1, t2);
    BAR8(); MMP(afB, 2, 6); VMW4(); BAR8();
    // P5
    LDB_ALL(1); LDA_H(1, afA, 0);
    STAGE8(1, 0, 0, t2);
    BAR8(); LGKM0(); MMP(afA, 0, 0); BAR8();
    // P6
    LDA_H(1, afB, 4);
    STAGE8(1, 0, 1, t2);
    BAR8(); LGKM0(); MMP(afA, 2, 2); BAR8();
    // P7
    STAGE8(0, 1, 0, t3);
    BAR8(); MMP(afB, 0, 4); BAR8();
    // P8
    STAGE8(0, 1, 1, t3);
    BAR8(); MMP(afB, 2, 6); VMW4(); BAR8();
  }

  __syncthreads();  // drain everything; LDS now reusable

  int b = by / 17;                 // KVLEN/256 = 17 tiles per batch
  int kk0 = m0 - b * KVLEN;

  if (n0 < DIMD) {
    // K: bounce C-tile through LDS (natural orientation), coalesced 16B stores
    #pragma unroll
    for (int mt = 0; mt < 8; mt++)
      #pragma unroll
      for (int nt = 0; nt < 4; nt++)
        #pragma unroll
        for (int r = 0; r < 4; r++) {
          int ml = wm * 128 + mt * 16 + l4 * 4 + r;
          int nl = wn * 64 + nt * 16 + lrow;
          lds[ml * 256 + (nl ^ ((ml & 15) << 4))] = f2bf(acc[mt][nt][r]);
        }
    __syncthreads();
    int ml = tid >> 1, nc = (tid & 1) * 128;
    #pragma unroll
    for (int j = 0; j < 16; j++) {
      int nn = nc + j * 8;
      int h = nn >> 6, d = nn & 63;
      bf16x8 v = *(const bf16x8*)&lds[ml * 256 + (nn ^ ((ml & 15) << 4))];
      *(bf16x8*)&kbuf[(((long)(b * HEADS + bx * 4 + h) * KVLEN + kk0 + ml) << 6) + d] = v;
    }
  } else {
    // V: bounce transposed, write vtbuf [b][h][d][kk] with 16B row stores
    #pragma unroll
    for (int mt = 0; mt < 8; mt++)
      #pragma unroll
      for (int nt = 0; nt < 4; nt++)
        #pragma unroll
        for (int r = 0; r < 4; r++) {
          int nl = wn * 64 + nt * 16 + lrow;
          int ml = wm * 128 + mt * 16 + l4 * 4 + r;
          lds[nl * 256 + (ml ^ ((nl & 15) << 4))] = f2bf(acc[mt][nt][r]);
        }
    __syncthreads();
    int nl = tid >> 1, mc = (tid & 1) * 128;
    int h = bx * 4 + (nl >> 6) - HEADS;
    int d = nl & 63;
    unsigned short* op = vtbuf + ((long)(b * HEADS + h) * DHD + d) * KVLEN + kk0 + mc;
    #pragma unroll
    for (int j = 0; j < 16; j++) {
      bf16x8 v = *(const bf16x8*)&lds[nl * 256 + ((mc + j * 8) ^ ((nl & 15) << 4))];
      *(bf16x8*)(op + j * 8) = v;
    }
  }
}

// ---------------- small GEMM: 128x64 tile, BK=32 (Q and OUT projections) ----------------
__global__ __launch_bounds__(256) void gemm3(
    const unsigned short* __restrict__ A, const unsigned short* __restrict__ BT,
    int mode, unsigned short* __restrict__ obf, float* __restrict__ of32)
{
  __shared__ unsigned short As[128 * 32];
  __shared__ unsigned short Bs[64 * 32];
  const int K = DIMD;
  int tid = threadIdx.x, l = tid & 63, w = tid >> 6;
  int m0 = blockIdx.y * 128, n0 = blockIdx.x * 64;
  int lrow = l & 15, lk = (l >> 4) * 8;

  int sr = l >> 2, scol = (l & 3) * 8;
  long am0 = m0 + w * 16 + sr, am1 = m0 + (w + 4) * 16 + sr;
  if (mode == 0) {
    am0 = (am0 >> 8) * KVLEN + N1 + (am0 & 255);
    am1 = (am1 >> 8) * KVLEN + N1 + (am1 & 255);
  }
  const unsigned short* gA0 = A + am0 * K + scol;
  const unsigned short* gA1 = A + am1 * K + scol;
  const unsigned short* gB = BT + (long)(n0 + w * 16 + sr) * K + scol;
  unsigned short* lA0 = As + w * 512;
  unsigned short* lA1 = As + (w + 4) * 512;
  unsigned short* lB = Bs + w * 512;

  f32x4 acc[2][4] = {};

  for (int k0 = 0; k0 < K; k0 += 32) {
    gload_lds16(gA0, lA0);
    gload_lds16(gA1, lA1);
    gload_lds16(gB, lB);
    gA0 += 32; gA1 += 32; gB += 32;
    __syncthreads();
    bf16x8 af[2], bfr[4];
    #pragma unroll
    for (int i = 0; i < 2; i++)
      af[i] = *reinterpret_cast<bf16x8*>(&As[(w * 32 + i * 16 + lrow) * 32 + lk]);
    #pragma unroll
    for (int j = 0; j < 4; j++)
      bfr[j] = *reinterpret_cast<bf16x8*>(&Bs[(j * 16 + lrow) * 32 + lk]);
    #pragma unroll
    for (int i = 0; i < 2; i++)
      #pragma unroll
      for (int j = 0; j < 4; j++)
        acc[i][j] = __builtin_amdgcn_mfma_f32_16x16x32_bf16(af[i], bfr[j], acc[i][j], 0, 0, 0);
    __syncthreads();
  }

  #pragma unroll
  for (int i = 0; i < 2; i++)
    #pragma unroll
    for (int j = 0; j < 4; j++)
      #pragma unroll
      for (int r = 0; r < 4; r++) {
        int m = m0 + w * 32 + i * 16 + (l >> 4) * 4 + r;
        int n = n0 + j * 16 + lrow;
        float v = acc[i][j][r];
        if (mode == 0) {
          int b = m >> 8, qq = m & 255, h = n >> 6, d = n & 63;
          obf[(((long)(b * HEADS + h) * N2 + qq) << 6) + d] = f2bf(v * 0.125f);
        } else {
          of32[(long)m * DIMD + n] = v;
        }
      }
}

// ---------------- flash attention: dbuf K/V, 1 barrier/iter, T14 async staging ----------------
// 1 block = (b,h, 64 q rows), 4 waves x 16 q rows. XCD-swizzled so the 4 q-tiles of a
// head co-reside on one XCD (K/V 2.2 MB -> L2-hit).
__global__ __launch_bounds__(256) void attn_kernel(
    const unsigned short* __restrict__ qb, const unsigned short* __restrict__ kb,
    const unsigned short* __restrict__ vtb, unsigned short* __restrict__ attn)
{
  __shared__ unsigned short Ks[2][64][72];
  __shared__ unsigned short Vs[2][64][72];
  __shared__ unsigned short Ps[4][16][72];
  int wgid = blockIdx.y * 4 + blockIdx.x;
  int orig = (wgid & 7) * 64 + (wgid >> 3);   // XCD k gets bh in [16k,16k+16)
  int qt = orig & 3, bh = orig >> 2;
  int tid = threadIdx.x, l = tid & 63, w = tid >> 6;
  int lrow = l & 15, lk = (l >> 4) * 8;

  const unsigned short* qp = qb + ((long)bh * N2 + qt * 64 + w * 16) * DHD;
  const unsigned short* kp = kb + (long)bh * KVLEN * DHD;
  const unsigned short* vp = vtb + (long)bh * DHD * KVLEN;

  bf16x8 qa[2];
  qa[0] = *reinterpret_cast<const bf16x8*>(qp + lrow * DHD + lk);
  qa[1] = *reinterpret_cast<const bf16x8*>(qp + lrow * DHD + 32 + lk);

  // per-thread staging coords: K rows krow/krow+32 (d-major), V rows = d
  int krow = tid >> 3, kcol = (tid & 7) * 8;

  f32x4 O[4] = {};
  float mrow[4] = {-1e30f, -1e30f, -1e30f, -1e30f};
  float lsum[4] = {0.f, 0.f, 0.f, 0.f};

  // prologue: tile 0 -> regs -> buf0
  bf16x8 kr0 = *(const bf16x8*)(kp + (long)krow * DHD + kcol);
  bf16x8 kr1 = *(const bf16x8*)(kp + (long)(32 + krow) * DHD + kcol);
  bf16x8 vr0 = *(const bf16x8*)(vp + (long)krow * KVLEN + kcol);
  bf16x8 vr1 = *(const bf16x8*)(vp + (long)(32 + krow) * KVLEN + kcol);
  *(bf16x8*)&Ks[0][krow][kcol] = kr0;
  *(bf16x8*)&Ks[0][32 + krow][kcol] = kr1;
  *(bf16x8*)&Vs[0][krow][kcol] = vr0;
  *(bf16x8*)&Vs[0][32 + krow][kcol] = vr1;

  const int NBLK = KVLEN / 64;
  int cur = 0;
  for (int blk = 0; blk < NBLK; blk++) {
    __syncthreads();  // buf[cur] visible to all waves
    if (blk + 1 < NBLK) {  // issue next-tile loads; they complete under this tile's compute
      const unsigned short* kn = kp + (long)((blk + 1) * 64) * DHD;
      const unsigned short* vn = vp + (blk + 1) * 64;
      kr0 = *(const bf16x8*)(kn + (long)krow * DHD + kcol);
      kr1 = *(const bf16x8*)(kn + (long)(32 + krow) * DHD + kcol);
      vr0 = *(const bf16x8*)(vn + (long)krow * KVLEN + kcol);
      vr1 = *(const bf16x8*)(vn + (long)(32 + krow) * KVLEN + kcol);
    }

    f32x4 S[4];
    __builtin_amdgcn_s_setprio(1);
    #pragma unroll
    for (int nt = 0; nt < 4; nt++) {
      f32x4 s = {};
      #pragma unroll
      for (int kt = 0; kt < 2; kt++) {
        bf16x8 bk = *reinterpret_cast<bf16x8*>(&Ks[cur][nt * 16 + lrow][kt * 32 + lk]);
        s = __builtin_amdgcn_mfma_f32_16x16x32_bf16(qa[kt], bk, s, 0, 0, 0);
      }
      S[nt] = s;  // Q pre-scaled by 0.125 at Q-GEMM epilogue
    }
    __builtin_amdgcn_s_setprio(0);

    float mx[4], rsum[4];
    #pragma unroll
    for (int r = 0; r < 4; r++) {
      float v = fmaxf(fmaxf(S[0][r], S[1][r]), fmaxf(S[2][r], S[3][r]));
      #pragma unroll
      for (int off = 1; off < 16; off <<= 1) v = fmaxf(v, __shfl_xor(v, off));
      mx[r] = v;
    }
    float fac[4];
    #pragma unroll
    for (int r = 0; r < 4; r++) {
      float mn = fmaxf(mrow[r], mx[r]);
      fac[r] = exp2f((mrow[r] - mn) * L2E);
      mrow[r] = mn;
      rsum[r] = 0.f;
    }
    #pragma unroll
    for (int nt = 0; nt < 4; nt++)
      #pragma unroll
      for (int r = 0; r < 4; r++) {
        float p = exp2f((S[nt][r] - mrow[r]) * L2E);
        rsum[r] += p;
        Ps[w][(l >> 4) * 4 + r][nt * 16 + lrow] = f2bf(p);
      }
    #pragma unroll
    for (int r = 0; r < 4; r++) {
      float v = rsum[r];
      #pragma unroll
      for (int off = 1; off < 16; off <<= 1) v += __shfl_xor(v, off);
      lsum[r] = lsum[r] * fac[r] + v;
    }
    #pragma unroll
    for (int dt = 0; dt < 4; dt++)
      #pragma unroll
      for (int r = 0; r < 4; r++) O[dt][r] *= fac[r];

    asm volatile("s_waitcnt lgkmcnt(0)" ::: "memory");
    bf16x8 pa[2];
    pa[0] = *reinterpret_cast<bf16x8*>(&Ps[w][lrow][lk]);
    pa[1] = *reinterpret_cast<bf16x8*>(&Ps[w][lrow][32 + lk]);
    __builtin_amdgcn_s_setprio(1);
    #pragma unroll
    for (int dt = 0; dt < 4; dt++)
      #pragma unroll
      for (int kt = 0; kt < 2; kt++) {
        bf16x8 bv = *reinterpret_cast<bf16x8*>(&Vs[cur][dt * 16 + lrow][kt * 32 + lk]);
        O[dt] = __builtin_amdgcn_mfma_f32_16x16x32_bf16(pa[kt], bv, O[dt], 0, 0, 0);
      }
    __builtin_amdgcn_s_setprio(0);

    if (blk + 1 < NBLK) {  // write staged regs into the other buffer
      *(bf16x8*)&Ks[cur ^ 1][krow][kcol] = kr0;
      *(bf16x8*)&Ks[cur ^ 1][32 + krow][kcol] = kr1;
      *(bf16x8*)&Vs[cur ^ 1][krow][kcol] = vr0;
      *(bf16x8*)&Vs[cur ^ 1][32 + krow][kcol] = vr1;
    }
    cur ^= 1;
  }

  int b = bh >> 4, h = bh & 15;
  #pragma unroll
  for (int dt = 0; dt < 4; dt++)
    #pragma unroll
    for (int r = 0; r < 4; r++) {
      int grow = b * N2 + qt * 64 + w * 16 + (l >> 4) * 4 + r;
      int col = h * DHD + dt * 16 + lrow;
      attn[(long)grow * DIMD + col] = f2bf(O[dt][r] / lsum[r]);
    }
}

// ---------------- launch ----------------
extern "C" void kernel_launch(void* const* d_in, const int* in_sizes, int n_in,
                              void* d_out, int out_size, void* d_ws, size_t ws_size,
                              hipStream_t stream) {
  const float* x    = (const float*)d_in[0];
  const float* lat  = (const float*)d_in[1];
  const float* g1   = (const float*)d_in[2];
  const float* b1   = (const float*)d_in[3];
  const float* g2   = (const float*)d_in[4];
  const float* b2   = (const float*)d_in[5];
  const float* Wq   = (const float*)d_in[6];
  const float* Wkv  = (const float*)d_in[7];
  const float* Wout = (const float*)d_in[8];
  float* out = (float*)d_out;

  char* ws = (char*)d_ws;
  size_t off = 0;
  auto alloc = [&](size_t bytes) -> void* {
    void* p = ws + off;
    off += (bytes + 255) & ~(size_t)255;
    return p;
  };
  unsigned short* kvin  = (unsigned short*)alloc((size_t)NB * KVLEN * DIMD * 2);
  unsigned short* WqT   = (unsigned short*)alloc((size_t)DIMD * DIMD * 2);
  unsigned short* WkvT  = (unsigned short*)alloc((size_t)2 * DIMD * DIMD * 2);
  unsigned short* WoutT = (unsigned short*)alloc((size_t)DIMD * DIMD * 2);
  unsigned short* qbuf  = (unsigned short*)alloc((size_t)NB * N2 * DIMD * 2);
  unsigned short* kbuf  = (unsigned short*)alloc((size_t)NB * HEADS * KVLEN * DHD * 2);
  unsigned short* vtbuf = (unsigned short*)alloc((size_t)NB * HEADS * KVLEN * DHD * 2);
  unsigned short* attn  = (unsigned short*)alloc((size_t)NB * N2 * DIMD * 2);
  if (off > ws_size) return;

  // weights -> bf16 [N][K]
  transpose_bf16<<<dim3(DIMD / 32, DIMD / 32), dim3(32, 8), 0, stream>>>(Wq, WqT, DIMD, DIMD);
  transpose_bf16<<<dim3(2 * DIMD / 32, DIMD / 32), dim3(32, 8), 0, stream>>>(Wkv, WkvT, DIMD, 2 * DIMD);
  transpose_bf16<<<dim3(DIMD / 32, DIMD / 32), dim3(32, 8), 0, stream>>>(Wout, WoutT, DIMD, DIMD);

  // layernorms into combined kv-input buffer
  ln_kernel<<<NB * N1, 256, 0, stream>>>(x, g1, b1, kvin, N1, 0);
  ln_kernel<<<NB * N2, 256, 0, stream>>>(lat, g2, b2, kvin, N2, N1);

  // Q = ln @ Wq (M=2048, N=1024), pre-scaled 0.125
  gemm3<<<dim3(16, 16), 256, 0, stream>>>(kvin, WqT, 0, qbuf, nullptr);
  // KV = [xn;ln] @ Wkv (M=34816, N=2048): K -> kbuf, V -> vtbuf (transposed in-kernel)
  gemm8<<<dim3(8, 136), 512, 0, stream>>>(kvin, WkvT, kbuf, vtbuf);
  // attention
  attn_kernel<<<dim3(4, NB * HEADS), 256, 0, stream>>>(qbuf, kbuf, vtbuf, attn);
  // out = attn @ Wout (M=2048, N=1024) -> f32
  gemm3<<<dim3(16, 16), 256, 0, stream>>>(attn, WoutT, 2, nullptr, out);
}